// Round 5
// baseline (331.444 us; speedup 1.0000x reference)
//
#include <hip/hip_runtime.h>
#include <cstdint>
#include <cmath>

// ---------------------------------------------------------------------------
// LlamaAttention round 12: GEMM BK=64 + flash softmax de-shuffle.
//   B=2 L=2048 D=2048 H=16 KV=4 DH=128, causal + key-padding mask, RoPE.
// R11 POST-MORTEM: flash 82us, ~4k cy/block-round vs ~2.2k of pipe work =>
//   still per-round serial-latency-bound; softmax chain holds 4 serial
//   cross-lane shuffles (ds-permute ~60cy each). Totals say GEMMs ~160us
//   combined (~640/430 TF) - the biggest remaining chunk; BK=32 pays the
//   barrier drain 64x per block (m233: 2-phase cost is ~72% stage+barrier).
// R12:
//   GEMM: BK 32->64 (barrier events halve; 8 gld16/step; LDS 32KB keeps
//     3 blocks/CU; inner loop = two sequential 32-col substeps, frags stay 8).
//   Flash (R11 structure kept verbatim otherwise):
//     - defer-max check uses PER-LANE partial max (__all reduces across the
//       wave; equivalent) -> the 2 max-shuffles move inside the rare branch.
//     - l_i kept lane-partial (per-quad); the 2 sum-shuffles move to the
//       epilogue (once per kernel). Common path has ZERO cross-lane ops.
//     - T5 s_setprio(1) around QK and PV MFMA clusters.
// MFMA layouts (learn_hip m89/m91): A[m=l15][k], B[k][n=l15],
//   C/D: col=l15, row=quad*4+reg (shape-determined).
// ---------------------------------------------------------------------------

typedef __bf16 bf16_t;
typedef __bf16 bf16x8 __attribute__((ext_vector_type(8)));
typedef __bf16 bf16x4 __attribute__((ext_vector_type(4)));
typedef float  f32x4  __attribute__((ext_vector_type(4)));

#define HQ   16
#define HKV  4
#define GQA  4
#define DHD  128
#define BB   2
#define LL   2048
#define DDIM 2048
#define MINV (-1e15f)
// 1/sqrt(128) * log2(e): folded into Q at RoPE time so softmax uses exp2.
#define QSC  0.12751744f

static __device__ __forceinline__ f32x4 mfma16(bf16x8 a, bf16x8 b, f32x4 c) {
  return __builtin_amdgcn_mfma_f32_16x16x32_bf16(a, b, c, 0, 0, 0);
}

// K=16 bf16 MFMA (PV step): A/B are 4 bf16 per lane, k = quad*4+j.
static __device__ __forceinline__ f32x4 mfma16k16(bf16x4 a, bf16x4 b, f32x4 c) {
#if __has_builtin(__builtin_amdgcn_mfma_f32_16x16x16bf16_1k)
  typedef short s4 __attribute__((ext_vector_type(4)));
  union U { bf16x4 h; s4 s; };
  U ua, ub; ua.h = a; ub.h = b;
  return __builtin_amdgcn_mfma_f32_16x16x16bf16_1k(ua.s, ub.s, c, 0, 0, 0);
#elif __has_builtin(__builtin_amdgcn_mfma_f32_16x16x16_bf16)
  return __builtin_amdgcn_mfma_f32_16x16x16_bf16(a, b, c, 0, 0, 0);
#else
  f32x4 d;
  asm volatile("v_mfma_f32_16x16x16_bf16 %0, %1, %2, %3"
               : "=v"(d) : "v"(a), "v"(b), "v"(c));
  return d;
#endif
}

#if __has_builtin(__builtin_amdgcn_exp2f)
#define EXP2F(x) __builtin_amdgcn_exp2f(x)
#else
#define EXP2F(x) exp2f(x)
#endif

static __device__ __forceinline__ void gld16(const bf16_t* g, bf16_t* l) {
  __builtin_amdgcn_global_load_lds(
      (const __attribute__((address_space(1))) void*)g,
      (__attribute__((address_space(3))) void*)l,
      16, 0, 0);
}

// ---------------- f32 -> bf16 cast (5 tensors in one launch) ----------------
struct CastArgs {
  const float* s[5];
  bf16_t* d[5];
  int n[5];
};

__global__ __launch_bounds__(256) void cast5_kernel(CastArgs a) {
  const int t = blockIdx.y;
  const int i8 = (blockIdx.x * 256 + threadIdx.x) * 8;
  if (i8 >= a.n[t]) return;
  const float4* s = (const float4*)(a.s[t] + i8);
  float4 x = s[0], y = s[1];
  bf16x8 o = {(bf16_t)x.x, (bf16_t)x.y, (bf16_t)x.z, (bf16_t)x.w,
              (bf16_t)y.x, (bf16_t)y.y, (bf16_t)y.z, (bf16_t)y.w};
  *(bf16x8*)(a.d[t] + i8) = o;
}

// ---------------------------------------------------------------------------
// Tiled GEMM: C = A(MxK) * W(NxK)^T, 128x128 tile, BK=64 (R12: barrier count
// halved vs BK=32; LDS 32KB -> still 3 blocks/CU; two 32-col MFMA substeps).
// Staging: thread stages rows wave*8+(lane>>3)+p*32, col-chunk (lane&7)*8;
//   LDS dest = As + wave*512 + p*2048 (+16B*lane implied): wave-uniform base
//   + lane*16 matches row-major [128][64] exactly (m104 constraint).
// STORE 2: f32 row-major -> C0.
// STORE 3: fused QKV epilogue (N=3072): cols [0,2048) -> C0 bf16 row-major;
//   [2048,2560) -> Ck bf16 row-major (N=512); [2560,3072) -> Cv transposed
//   (B,KV,DH,L) with bf16x4 packed stores along L.
// ---------------------------------------------------------------------------
template <int STORE>
__global__ __launch_bounds__(256) void gemm_tile(const bf16_t* __restrict__ A,
                                                 const bf16_t* __restrict__ W,
                                                 void* __restrict__ C0,
                                                 bf16_t* __restrict__ Ck,
                                                 bf16_t* __restrict__ Cv,
                                                 int M, int N, int K) {
  __shared__ __align__(16) bf16_t As[128 * 64];
  __shared__ __align__(16) bf16_t Bs[128 * 64];
  const int tid  = threadIdx.x;
  const int lane = tid & 63;
  const int wave = tid >> 6;
  const int l15  = lane & 15;
  const int quad = lane >> 4;
  const int m0 = blockIdx.y * 128;
  const int n0 = blockIdx.x * 128;

  const int srow = wave * 8 + (lane >> 3);   // 0..31
  const int scol = (lane & 7) * 8;           // 0..56
  const bf16_t* ag = A + (size_t)(m0 + srow) * K + scol;
  const bf16_t* wg = W + (size_t)(n0 + srow) * K + scol;
  bf16_t* al = As + wave * 512;
  bf16_t* bl = Bs + wave * 512;

  const int wm = (wave >> 1) * 64;
  const int wn = (wave & 1) * 64;

  f32x4 acc[4][4];
#pragma unroll
  for (int mi = 0; mi < 4; mi++)
#pragma unroll
    for (int ni = 0; ni < 4; ni++) acc[mi][ni] = {0.f, 0.f, 0.f, 0.f};

  for (int k0 = 0; k0 < K; k0 += 64) {
    __syncthreads();
#pragma unroll
    for (int p = 0; p < 4; p++) {
      gld16(ag + k0 + (size_t)(p * 32) * K, al + p * 2048);
      gld16(wg + k0 + (size_t)(p * 32) * K, bl + p * 2048);
    }
    __syncthreads();
#pragma unroll
    for (int c = 0; c < 2; c++) {
      bf16x8 af[4], bfr[4];
#pragma unroll
      for (int mi = 0; mi < 4; mi++)
        af[mi] = *(const bf16x8*)(As + (wm + mi * 16 + l15) * 64 + c * 32 + quad * 8);
#pragma unroll
      for (int ni = 0; ni < 4; ni++)
        bfr[ni] = *(const bf16x8*)(Bs + (wn + ni * 16 + l15) * 64 + c * 32 + quad * 8);
#pragma unroll
      for (int mi = 0; mi < 4; mi++)
#pragma unroll
        for (int ni = 0; ni < 4; ni++)
          acc[mi][ni] = mfma16(af[mi], bfr[ni], acc[mi][ni]);
    }
  }

  if (STORE == 2) {
    float* C = (float*)C0;
#pragma unroll
    for (int mi = 0; mi < 4; mi++) {
      const int row = m0 + wm + mi * 16 + quad * 4;
#pragma unroll
      for (int ni = 0; ni < 4; ni++) {
        const int col = n0 + wn + ni * 16 + l15;
#pragma unroll
        for (int i = 0; i < 4; i++)
          C[(size_t)(row + i) * N + col] = acc[mi][ni][i];
      }
    }
  } else {  // STORE == 3
    if (n0 < 2048) {
      bf16_t* C = (bf16_t*)C0;
#pragma unroll
      for (int mi = 0; mi < 4; mi++) {
        const int row = m0 + wm + mi * 16 + quad * 4;
#pragma unroll
        for (int ni = 0; ni < 4; ni++) {
          const int col = n0 + wn + ni * 16 + l15;
#pragma unroll
          for (int i = 0; i < 4; i++)
            C[(size_t)(row + i) * 2048 + col] = (bf16_t)acc[mi][ni][i];
        }
      }
    } else if (n0 < 2560) {
#pragma unroll
      for (int mi = 0; mi < 4; mi++) {
        const int row = m0 + wm + mi * 16 + quad * 4;
#pragma unroll
        for (int ni = 0; ni < 4; ni++) {
          const int col = n0 - 2048 + wn + ni * 16 + l15;
#pragma unroll
          for (int i = 0; i < 4; i++)
            Ck[(size_t)(row + i) * 512 + col] = (bf16_t)acc[mi][ni][i];
        }
      }
    } else {
#pragma unroll
      for (int mi = 0; mi < 4; mi++) {
        const int row = m0 + wm + mi * 16 + quad * 4;
        const int b = row >> 11;
        const int l0 = row & (LL - 1);
#pragma unroll
        for (int ni = 0; ni < 4; ni++) {
          const int kvcol = n0 - 2560 + wn + ni * 16 + l15;
          const int kvh = kvcol >> 7, d = kvcol & 127;
          bf16x4 w4 = {(bf16_t)acc[mi][ni][0], (bf16_t)acc[mi][ni][1],
                       (bf16_t)acc[mi][ni][2], (bf16_t)acc[mi][ni][3]};
          *(bf16x4*)(Cv + ((size_t)(b * HKV + kvh) * DHD + d) * LL + l0) = w4;
        }
      }
    }
  }
}

// In-place RoPE on q,k + padding-bias fill. One thread per (b,l,head,dpair).
// Q additionally pre-scaled by QSC = 1/sqrt(DH)*log2(e) (flash uses exp2).
__global__ void rope_kernel(bf16_t* __restrict__ q, bf16_t* __restrict__ k,
                            const int* __restrict__ amask, float* __restrict__ bias) {
  const int nq = BB * LL * HQ * 64;
  const int nk = BB * LL * HKV * 64;
  int id = blockIdx.x * blockDim.x + threadIdx.x;
  if (id >= nq + nk) {
    int id2 = id - (nq + nk);
    if (id2 < BB * LL) bias[id2] = (amask[id2] == 0) ? MINV : 0.0f;
    return;
  }
  bf16_t* base;
  int heads, idx;
  float sc;
  if (id < nq) { base = q; heads = HQ; idx = id; sc = QSC; }
  else         { base = k; heads = HKV; idx = id - nq; sc = 1.0f; }
  int d = idx & 63; idx >>= 6;
  int hh = idx % heads;
  int bl = idx / heads;      // b*LL + l
  int l = bl & (LL - 1);
  bf16_t* p = base + ((size_t)bl * heads + hh) * DHD + d;
  float x1 = (float)p[0];
  float x2 = (float)p[64];
  // invf = 10000^(-d/64) = exp(-d * ln(10000)/64)
  float invf = __expf(-(float)d * 0.14391156862532788f);
  float fr = (float)l * invf;
  float s, c;
  __sincosf(fr, &s, &c);
  p[0]  = (bf16_t)((x1 * c - x2 * s) * sc);
  p[64] = (bf16_t)((x2 * c + x1 * s) * sc);
}

// ---------------------------------------------------------------------------
// Flash attention: 512 blocks x 512 threads (8 waves). Block owns 128-row
// tile pair {c, 31-c}: waves 0-3 -> tile c (16-row strips), waves 4-7 ->
// tile 31-c. KV round = 64 keys, double-buffered LDS, 1 barrier/round.
// Kbuf[key 0..63][d 0..127] bf16, row 256B, byte ^= (row&7)<<4 swizzle.
// Vbuf[d 0..127][key-col 0..63] bf16, row 128B, same swizzle, with column
// permutation so a b128 read at col kt2*32+quad*8 yields K=16 A-frags for
// kt=2*kt2, 2*kt2+1. P register-resident (S^T lane layout = K=16 B-frag).
// Round r: issue loads r+1 -> compute buf[cur] -> write buf[cur^1] -> sync.
// R12: softmax common path has no cross-lane ops (per-lane defer check;
// lane-partial l_i reduced once in the epilogue); setprio around MFMA.
// ---------------------------------------------------------------------------
__global__ __launch_bounds__(512, 4) void flash_attn2(const bf16_t* __restrict__ q,
                                                      const bf16_t* __restrict__ k,
                                                      const bf16_t* __restrict__ vt,
                                                      const float* __restrict__ bias,
                                                      bf16_t* __restrict__ o) {
  __shared__ __align__(16) bf16_t Kbuf[2][64 * 128];   // 2 x 16 KB swizzled
  __shared__ __align__(16) bf16_t Vbuf[2][128 * 64];   // 2 x 16 KB swizzled
  __shared__ __align__(16) float  Bb[2048];            // 8 KB bias row

  const int tid  = threadIdx.x;
  const int lane = tid & 63;
  const int wave = tid >> 6;
  const int l15  = lane & 15;
  const int quad = lane >> 4;

  // 512 blocks, 2/CU: co-resident pair {i, i+256} -> c and 15-c
  // (rounds (32-c) + (17+c) = 49, balanced per CU).
  const int bi   = blockIdx.x;
  const int half = bi >> 8;
  const int jj   = bi & 255;
  const int cc   = jj >> 5;
  const int c    = half ? (15 - cc) : cc;          // 0..15
  const int bh = jj & 31;
  const int b  = bh >> 4;
  const int h  = bh & 15;
  const int kv = h >> 2;

  const int tile = (wave < 4) ? c : (31 - c);      // 64-row tile index
  const int q0   = tile * 64 + (wave & 3) * 16;    // this wave's 16-row strip
  const int nrounds = 32 - c;                      // 17..32

  bf16x8 qf[4];
  {
    const bf16_t* qb = q + ((size_t)(b * LL + q0 + l15)) * (HQ * DHD) + h * DHD + quad * 8;
#pragma unroll
    for (int t = 0; t < 4; t++) qf[t] = *(const bf16x8*)(qb + 32 * t);
  }

  f32x4 acc[8];
#pragma unroll
  for (int mt = 0; mt < 8; mt++) acc[mt] = {0.f, 0.f, 0.f, 0.f};
  float m_i = -1e30f;      // per-row (uniform across the row's 4 quads)
  float l_i = 0.f;         // LANE-PARTIAL (this quad's keys); reduced at end

  const bf16_t* kg_base = k + ((size_t)(b * LL)) * (HKV * DHD) + kv * DHD;
  const bf16_t* vg_base = vt + ((size_t)(b * HKV + kv) * DHD) * LL;
  const float*  bias_b  = bias + b * LL;

  // Bias row -> LDS (8 KB once; 512 float4 = 2048 floats).
  ((float4*)Bb)[tid] = ((const float4*)bias_b)[tid];

  // Staging split across 512 threads: K 64x128 (2 chunks of 32 rows),
  // V^T 128x64 (2 chunks of 64 d-rows).
  const int krow = tid >> 4, kch = tid & 15;       // krow 0..31
  const int vrow = tid >> 3, vch = tid & 7;        // vrow 0..63
  // V column permutation for the low half of a bf16x8 global chunk at vch:
  // keys 8*vch+m -> col c(k); high half lands at +8 elems (+16 bytes).
  const int vc0  = ((vch >> 2) << 5) + (((vch << 1) & 3) << 3) + (((vch >> 1) & 1) << 2);
  const int vblo = vc0 * 2;                 // byte offset in 128B row
  const int ksw  = (krow & 7) << 4;         // row&7 preserved by +32 chunks
  const int vsw  = (vrow & 7) << 4;         // row&7 preserved by +64 chunks
  const int rsw  = (l15 & 7) << 4;          // read-side swizzle (row = *16+l15)

  const bf16_t* kg0 = kg_base + (size_t)krow * (HKV * DHD) + kch * 8;
  const bf16_t* vg0 = vg_base + (size_t)vrow * LL + vch * 8;

  bf16x8 kl[2], vl[2];
  auto ISSUE = [&](int j0) {
#pragma unroll
    for (int p = 0; p < 2; p++)
      kl[p] = *(const bf16x8*)(kg0 + (size_t)(j0 + p * 32) * (HKV * DHD));
#pragma unroll
    for (int p = 0; p < 2; p++)
      vl[p] = *(const bf16x8*)(vg0 + j0 + (size_t)p * 64 * LL);
  };
  auto STAGE = [&](int bsel) {
    char* kb = (char*)(&Kbuf[bsel][0]);
    char* vb = (char*)(&Vbuf[bsel][0]);
#pragma unroll
    for (int p = 0; p < 2; p++)
      *(bf16x8*)(kb + (size_t)(krow + p * 32) * 256 + ((kch * 16) ^ ksw)) = kl[p];
#pragma unroll
    for (int p = 0; p < 2; p++) {
      char* vbase = vb + (size_t)(vrow + p * 64) * 128;
      bf16x4 lo4 = __builtin_shufflevector(vl[p], vl[p], 0, 1, 2, 3);
      bf16x4 hi4 = __builtin_shufflevector(vl[p], vl[p], 4, 5, 6, 7);
      *(bf16x4*)(vbase + (vblo ^ vsw)) = lo4;
      *(bf16x4*)(vbase + ((vblo + 16) ^ vsw)) = hi4;
    }
  };

  // Prologue: stage round 0 into buf0.
  ISSUE(0);
  STAGE(0);
  __syncthreads();

  int cur = 0;
  for (int r = 0; r < nrounds; r++) {
    const int j0 = r * 64;
    const bool last = (r + 1 >= nrounds);
    if (!last) ISSUE(j0 + 64);   // issue-early: lands during compute (T14)

    const bool act = (j0 <= q0 + 15);   // wave-uniform
    if (act) {
      const char* KbC = (const char*)(&Kbuf[cur][0]);
      const char* VbC = (const char*)(&Vbuf[cur][0]);

      // ---- QK^T (S^T): A = K row, B = Q^T; D row = key (quad*4+i), col = qrow.
      f32x4 s[4];
      __builtin_amdgcn_s_setprio(1);
#pragma unroll
      for (int kt = 0; kt < 4; kt++) {
        const char* kr = KbC + (size_t)(kt * 16 + l15) * 256;
        f32x4 s0 = {0.f, 0.f, 0.f, 0.f};
#pragma unroll
        for (int t = 0; t < 4; t++) {
          bf16x8 kf = *(const bf16x8*)(kr + ((quad * 16 + t * 64) ^ rsw));
          s0 = mfma16(kf, qf[t], s0);
        }
        s[kt] = s0;
      }
      __builtin_amdgcn_s_setprio(0);

      // ---- online softmax in log2 domain (Q pre-scaled by QSC). P stays in
      //      registers: lane's p4 per kt IS the K=16 B-frag for PV.
      const int qrow = q0 + l15;
      const bool diag = (j0 + 63 > q0);      // mask iff max key > min row
      float mx = -1e30f;                     // per-lane partial max
#pragma unroll
      for (int kt = 0; kt < 4; kt++) {
        f32x4 sv = s[kt];
        f32x4 bv = *(const f32x4*)(&Bb[j0 + kt * 16 + quad * 4]);
#pragma unroll
        for (int i = 0; i < 4; i++) {
          float x = sv[i] + bv[i];
          if (diag) {
            int key = j0 + kt * 16 + quad * 4 + i;
            if (key > qrow) x = MINV;
          }
          sv[i] = x;
          mx = fmaxf(mx, x);
        }
        s[kt] = sv;
      }
      // defer-max (T13) with PER-LANE partial max: __all() reduces across the
      // wave, so this is equivalent to checking the row-reduced max. The two
      // max-shuffles only run on the rare rescale path.
      if (!__all(mx <= m_i + 8.0f)) {
        mx = fmaxf(mx, __shfl_xor(mx, 16));
        mx = fmaxf(mx, __shfl_xor(mx, 32));   // now per-row max
        const float mn = fmaxf(m_i, mx);
        const float alpha = EXP2F(m_i - mn);
        m_i = mn;
        l_i *= alpha;
#pragma unroll
        for (int mt = 0; mt < 8; mt++) {
          acc[mt][0] *= alpha; acc[mt][1] *= alpha;
          acc[mt][2] *= alpha; acc[mt][3] *= alpha;
        }
      }
      const float mn = m_i;
      float sum = 0.f;
      bf16x4 pf[4];
#pragma unroll
      for (int kt = 0; kt < 4; kt++) {
        f32x4 sv = s[kt];
        bf16x4 p4;
#pragma unroll
        for (int i = 0; i < 4; i++) {
          float pe = EXP2F(sv[i] - mn);
          sum += pe;
          p4[i] = (bf16_t)pe;
        }
        pf[kt] = p4;
      }
      l_i += sum;    // lane-partial; cross-quad reduce deferred to epilogue

      // ---- PV with K=16 MFMA: A = V^T frag (k=quad*4+j via permuted cols),
      //      B = pf (lane-local). acc layout: row=d (mt*16+quad*4+i), col=qrow.
      __builtin_amdgcn_s_setprio(1);
#pragma unroll
      for (int mt = 0; mt < 8; mt++) {
        const char* vr = VbC + (size_t)(mt * 16 + l15) * 128;
        bf16x8 v01 = *(const bf16x8*)(vr + ((quad * 16) ^ rsw));
        bf16x8 v23 = *(const bf16x8*)(vr + ((64 + quad * 16) ^ rsw));
        bf16x4 va = __builtin_shufflevector(v01, v01, 0, 1, 2, 3);
        bf16x4 vb = __builtin_shufflevector(v01, v01, 4, 5, 6, 7);
        bf16x4 vc = __builtin_shufflevector(v23, v23, 0, 1, 2, 3);
        bf16x4 vd = __builtin_shufflevector(v23, v23, 4, 5, 6, 7);
        acc[mt] = mfma16k16(va, pf[0], acc[mt]);
        acc[mt] = mfma16k16(vb, pf[1], acc[mt]);
        acc[mt] = mfma16k16(vc, pf[2], acc[mt]);
        acc[mt] = mfma16k16(vd, pf[3], acc[mt]);
      }
      __builtin_amdgcn_s_setprio(0);
    }

    // ---- stage round r+1 into the other buffer; single barrier per round.
    if (!last) {
      STAGE(cur ^ 1);
      __syncthreads();
      cur ^= 1;
    }
  }

  {
    // Epilogue: reduce the lane-partial l_i across the row's 4 quads (once).
    l_i += __shfl_xor(l_i, 16);
    l_i += __shfl_xor(l_i, 32);
    const float invl = 1.0f / l_i;
    bf16_t* ob = o + ((size_t)(b * LL + q0 + l15)) * (HQ * DHD) + h * DHD + quad * 4;
#pragma unroll
    for (int mt = 0; mt < 8; mt++) {
      f32x4 a = acc[mt];
      bf16x4 w = {(bf16_t)(a[0] * invl), (bf16_t)(a[1] * invl),
                  (bf16_t)(a[2] * invl), (bf16_t)(a[3] * invl)};
      *(bf16x4*)(ob + mt * 16) = w;
    }
  }
}

extern "C" void kernel_launch(void* const* d_in, const int* in_sizes, int n_in,
                              void* d_out, int out_size, void* d_ws, size_t ws_size,
                              hipStream_t stream) {
  const float* hidden = (const float*)d_in[0];
  const int*   amask  = (const int*)d_in[1];
  const float* Wq     = (const float*)d_in[2];
  const float* Wk     = (const float*)d_in[3];
  const float* Wv     = (const float*)d_in[4];
  const float* Wo     = (const float*)d_in[5];
  float* out = (float*)d_out;

  const int M = BB * LL;           // 4096
  const size_t MB = 1u << 20;
  char* ws = (char*)d_ws;
  bf16_t* hid_b   = (bf16_t*)(ws);            // 16 MB  (B,L,D)
  bf16_t* q_ws    = (bf16_t*)(ws + 16 * MB);  // 16 MB
  bf16_t* attn_ws = (bf16_t*)(ws + 32 * MB);  // 16 MB
  bf16_t* k_ws    = (bf16_t*)(ws + 48 * MB);  //  4 MB
  bf16_t* vt_ws   = (bf16_t*)(ws + 52 * MB);  //  4 MB
  bf16_t* wqkv_b  = (bf16_t*)(ws + 56 * MB);  // 12 MB: Wq(8) + Wk(2) + Wv(2)
  bf16_t* wq_b    = wqkv_b;
  bf16_t* wk_b    = (bf16_t*)(ws + 64 * MB);
  bf16_t* wv_b    = (bf16_t*)(ws + 66 * MB);
  bf16_t* wo_b    = (bf16_t*)(ws + 68 * MB);  //  8 MB
  float*  bias_ws = (float*)(ws);             // 16 KB, aliases hid_b

  CastArgs ca;
  ca.s[0] = hidden; ca.d[0] = hid_b; ca.n[0] = BB * LL * DDIM;
  ca.s[1] = Wq;     ca.d[1] = wq_b;  ca.n[1] = HQ * DHD * DDIM;
  ca.s[2] = Wk;     ca.d[2] = wk_b;  ca.n[2] = HKV * DHD * DDIM;
  ca.s[3] = Wv;     ca.d[3] = wv_b;  ca.n[3] = HKV * DHD * DDIM;
  ca.s[4] = Wo;     ca.d[4] = wo_b;  ca.n[4] = DDIM * DDIM;
  {
    int maxn = BB * LL * DDIM;
    dim3 g((maxn / 8 + 255) / 256, 5);
    cast5_kernel<<<g, 256, 0, stream>>>(ca);
  }

  gemm_tile<3><<<dim3(3072 / 128, M / 128), 256, 0, stream>>>(
      hid_b, wqkv_b, q_ws, k_ws, vt_ws, M, 3072, DDIM);

  {
    int total = BB * LL * (HQ + HKV) * 64 + BB * LL;
    rope_kernel<<<(total + 255) / 256, 256, 0, stream>>>(q_ws, k_ws, amask, bias_ws);
  }

  flash_attn2<<<512, 512, 0, stream>>>(q_ws, k_ws, vt_ws, bias_ws, attn_ws);

  gemm_tile<2><<<dim3(DDIM / 128, M / 128), 256, 0, stream>>>(
      attn_ws, wo_b, (void*)out, nullptr, nullptr, M, DDIM, DDIM);
}

// Round 6
// 308.471 us; speedup vs baseline: 1.0745x; 1.0745x over previous
//
#include <hip/hip_runtime.h>
#include <cstdint>
#include <cmath>

// ---------------------------------------------------------------------------
// LlamaAttention round 13: revert GEMM to BK=32 (R11), keep R12 flash.
//   B=2 L=2048 D=2048 H=16 KV=4 DH=128, causal + key-padding mask, RoPE.
// R12 POST-MORTEM: BK=64 GEMM regressed QKV ~80->109us: LDS row stride
//   128B == 0 mod 128 => 16-way bank conflict on every frag ds_read_b128
//   (SQ_LDS_BANK_CONFLICT 18.9M, MfmaUtil 18.5%). m252: conflict fixes at
//   2-phase buy +2%, so the halved barrier count couldn't pay for it.
//   Total rose only +11.5 while QKV rose ~+29 => R12's flash de-shuffle
//   (+setprio) likely cut flash 82 -> ~60-70us. This round isolates it.
// R13: gemm_tile back to R11's BK=32 m97-structure verbatim; flash kept
//   from R12 (zero cross-lane ops on softmax common path, lane-partial l_i,
//   per-lane defer-max check, setprio around MFMA clusters).
// MFMA layouts (learn_hip m89/m91): A[m=l15][k], B[k][n=l15],
//   C/D: col=l15, row=quad*4+reg (shape-determined).
// ---------------------------------------------------------------------------

typedef __bf16 bf16_t;
typedef __bf16 bf16x8 __attribute__((ext_vector_type(8)));
typedef __bf16 bf16x4 __attribute__((ext_vector_type(4)));
typedef float  f32x4  __attribute__((ext_vector_type(4)));

#define HQ   16
#define HKV  4
#define GQA  4
#define DHD  128
#define BB   2
#define LL   2048
#define DDIM 2048
#define MINV (-1e15f)
// 1/sqrt(128) * log2(e): folded into Q at RoPE time so softmax uses exp2.
#define QSC  0.12751744f

static __device__ __forceinline__ f32x4 mfma16(bf16x8 a, bf16x8 b, f32x4 c) {
  return __builtin_amdgcn_mfma_f32_16x16x32_bf16(a, b, c, 0, 0, 0);
}

// K=16 bf16 MFMA (PV step): A/B are 4 bf16 per lane, k = quad*4+j.
static __device__ __forceinline__ f32x4 mfma16k16(bf16x4 a, bf16x4 b, f32x4 c) {
#if __has_builtin(__builtin_amdgcn_mfma_f32_16x16x16bf16_1k)
  typedef short s4 __attribute__((ext_vector_type(4)));
  union U { bf16x4 h; s4 s; };
  U ua, ub; ua.h = a; ub.h = b;
  return __builtin_amdgcn_mfma_f32_16x16x16bf16_1k(ua.s, ub.s, c, 0, 0, 0);
#elif __has_builtin(__builtin_amdgcn_mfma_f32_16x16x16_bf16)
  return __builtin_amdgcn_mfma_f32_16x16x16_bf16(a, b, c, 0, 0, 0);
#else
  f32x4 d;
  asm volatile("v_mfma_f32_16x16x16_bf16 %0, %1, %2, %3"
               : "=v"(d) : "v"(a), "v"(b), "v"(c));
  return d;
#endif
}

#if __has_builtin(__builtin_amdgcn_exp2f)
#define EXP2F(x) __builtin_amdgcn_exp2f(x)
#else
#define EXP2F(x) exp2f(x)
#endif

static __device__ __forceinline__ void gld16(const bf16_t* g, bf16_t* l) {
  __builtin_amdgcn_global_load_lds(
      (const __attribute__((address_space(1))) void*)g,
      (__attribute__((address_space(3))) void*)l,
      16, 0, 0);
}

// ---------------- f32 -> bf16 cast (5 tensors in one launch) ----------------
struct CastArgs {
  const float* s[5];
  bf16_t* d[5];
  int n[5];
};

__global__ __launch_bounds__(256) void cast5_kernel(CastArgs a) {
  const int t = blockIdx.y;
  const int i8 = (blockIdx.x * 256 + threadIdx.x) * 8;
  if (i8 >= a.n[t]) return;
  const float4* s = (const float4*)(a.s[t] + i8);
  float4 x = s[0], y = s[1];
  bf16x8 o = {(bf16_t)x.x, (bf16_t)x.y, (bf16_t)x.z, (bf16_t)x.w,
              (bf16_t)y.x, (bf16_t)y.y, (bf16_t)y.z, (bf16_t)y.w};
  *(bf16x8*)(a.d[t] + i8) = o;
}

// ---------------------------------------------------------------------------
// Tiled GEMM: C = A(MxK) * W(NxK)^T, 128x128 tile, BK=32 (m97 structure).
// STORE 2: f32 row-major -> C0.
// STORE 3: fused QKV epilogue (N=3072): cols [0,2048) -> C0 bf16 row-major;
//   [2048,2560) -> Ck bf16 row-major (N=512); [2560,3072) -> Cv transposed
//   (B,KV,DH,L) with bf16x4 packed stores along L.
// ---------------------------------------------------------------------------
template <int STORE>
__global__ __launch_bounds__(256) void gemm_tile(const bf16_t* __restrict__ A,
                                                 const bf16_t* __restrict__ W,
                                                 void* __restrict__ C0,
                                                 bf16_t* __restrict__ Ck,
                                                 bf16_t* __restrict__ Cv,
                                                 int M, int N, int K) {
  __shared__ __align__(16) bf16_t As[128 * 32];
  __shared__ __align__(16) bf16_t Bs[128 * 32];
  const int tid  = threadIdx.x;
  const int lane = tid & 63;
  const int wave = tid >> 6;
  const int l15  = lane & 15;
  const int quad = lane >> 4;
  const int m0 = blockIdx.y * 128;
  const int n0 = blockIdx.x * 128;

  const int srow = wave * 32 + (lane >> 2);
  const int scol = (lane & 3) * 8;
  const bf16_t* ag = A + (size_t)(m0 + srow) * K + scol;
  const bf16_t* wg = W + (size_t)(n0 + srow) * K + scol;
  bf16_t* al = As + wave * 1024;
  bf16_t* bl = Bs + wave * 1024;

  const int wm = (wave >> 1) * 64;
  const int wn = (wave & 1) * 64;

  f32x4 acc[4][4];
#pragma unroll
  for (int mi = 0; mi < 4; mi++)
#pragma unroll
    for (int ni = 0; ni < 4; ni++) acc[mi][ni] = {0.f, 0.f, 0.f, 0.f};

  for (int k0 = 0; k0 < K; k0 += 32) {
    __syncthreads();
    gld16(ag + k0, al);
    gld16(ag + k0 + (size_t)16 * K, al + 512);
    gld16(wg + k0, bl);
    gld16(wg + k0 + (size_t)16 * K, bl + 512);
    __syncthreads();
    bf16x8 af[4], bfr[4];
#pragma unroll
    for (int mi = 0; mi < 4; mi++)
      af[mi] = *(const bf16x8*)(As + (wm + mi * 16 + l15) * 32 + quad * 8);
#pragma unroll
    for (int ni = 0; ni < 4; ni++)
      bfr[ni] = *(const bf16x8*)(Bs + (wn + ni * 16 + l15) * 32 + quad * 8);
#pragma unroll
    for (int mi = 0; mi < 4; mi++)
#pragma unroll
      for (int ni = 0; ni < 4; ni++)
        acc[mi][ni] = mfma16(af[mi], bfr[ni], acc[mi][ni]);
  }

  if (STORE == 2) {
    float* C = (float*)C0;
#pragma unroll
    for (int mi = 0; mi < 4; mi++) {
      const int row = m0 + wm + mi * 16 + quad * 4;
#pragma unroll
      for (int ni = 0; ni < 4; ni++) {
        const int col = n0 + wn + ni * 16 + l15;
#pragma unroll
        for (int i = 0; i < 4; i++)
          C[(size_t)(row + i) * N + col] = acc[mi][ni][i];
      }
    }
  } else {  // STORE == 3
    if (n0 < 2048) {
      bf16_t* C = (bf16_t*)C0;
#pragma unroll
      for (int mi = 0; mi < 4; mi++) {
        const int row = m0 + wm + mi * 16 + quad * 4;
#pragma unroll
        for (int ni = 0; ni < 4; ni++) {
          const int col = n0 + wn + ni * 16 + l15;
#pragma unroll
          for (int i = 0; i < 4; i++)
            C[(size_t)(row + i) * 2048 + col] = (bf16_t)acc[mi][ni][i];
        }
      }
    } else if (n0 < 2560) {
#pragma unroll
      for (int mi = 0; mi < 4; mi++) {
        const int row = m0 + wm + mi * 16 + quad * 4;
#pragma unroll
        for (int ni = 0; ni < 4; ni++) {
          const int col = n0 - 2048 + wn + ni * 16 + l15;
#pragma unroll
          for (int i = 0; i < 4; i++)
            Ck[(size_t)(row + i) * 512 + col] = (bf16_t)acc[mi][ni][i];
        }
      }
    } else {
#pragma unroll
      for (int mi = 0; mi < 4; mi++) {
        const int row = m0 + wm + mi * 16 + quad * 4;
        const int b = row >> 11;
        const int l0 = row & (LL - 1);
#pragma unroll
        for (int ni = 0; ni < 4; ni++) {
          const int kvcol = n0 - 2560 + wn + ni * 16 + l15;
          const int kvh = kvcol >> 7, d = kvcol & 127;
          bf16x4 w4 = {(bf16_t)acc[mi][ni][0], (bf16_t)acc[mi][ni][1],
                       (bf16_t)acc[mi][ni][2], (bf16_t)acc[mi][ni][3]};
          *(bf16x4*)(Cv + ((size_t)(b * HKV + kvh) * DHD + d) * LL + l0) = w4;
        }
      }
    }
  }
}

// In-place RoPE on q,k + padding-bias fill. One thread per (b,l,head,dpair).
// Q additionally pre-scaled by QSC = 1/sqrt(DH)*log2(e) (flash uses exp2).
__global__ void rope_kernel(bf16_t* __restrict__ q, bf16_t* __restrict__ k,
                            const int* __restrict__ amask, float* __restrict__ bias) {
  const int nq = BB * LL * HQ * 64;
  const int nk = BB * LL * HKV * 64;
  int id = blockIdx.x * blockDim.x + threadIdx.x;
  if (id >= nq + nk) {
    int id2 = id - (nq + nk);
    if (id2 < BB * LL) bias[id2] = (amask[id2] == 0) ? MINV : 0.0f;
    return;
  }
  bf16_t* base;
  int heads, idx;
  float sc;
  if (id < nq) { base = q; heads = HQ; idx = id; sc = QSC; }
  else         { base = k; heads = HKV; idx = id - nq; sc = 1.0f; }
  int d = idx & 63; idx >>= 6;
  int hh = idx % heads;
  int bl = idx / heads;      // b*LL + l
  int l = bl & (LL - 1);
  bf16_t* p = base + ((size_t)bl * heads + hh) * DHD + d;
  float x1 = (float)p[0];
  float x2 = (float)p[64];
  // invf = 10000^(-d/64) = exp(-d * ln(10000)/64)
  float invf = __expf(-(float)d * 0.14391156862532788f);
  float fr = (float)l * invf;
  float s, c;
  __sincosf(fr, &s, &c);
  p[0]  = (bf16_t)((x1 * c - x2 * s) * sc);
  p[64] = (bf16_t)((x2 * c + x1 * s) * sc);
}

// ---------------------------------------------------------------------------
// Flash attention: 512 blocks x 512 threads (8 waves). Block owns 128-row
// tile pair {c, 31-c}: waves 0-3 -> tile c (16-row strips), waves 4-7 ->
// tile 31-c. KV round = 64 keys, double-buffered LDS, 1 barrier/round.
// Kbuf[key 0..63][d 0..127] bf16, row 256B, byte ^= (row&7)<<4 swizzle.
// Vbuf[d 0..127][key-col 0..63] bf16, row 128B, same swizzle, with column
// permutation so a b128 read at col kt2*32+quad*8 yields K=16 A-frags for
// kt=2*kt2, 2*kt2+1. P register-resident (S^T lane layout = K=16 B-frag).
// Round r: issue loads r+1 -> compute buf[cur] -> write buf[cur^1] -> sync.
// Softmax common path has no cross-lane ops (per-lane defer check;
// lane-partial l_i reduced once in the epilogue); setprio around MFMA.
// ---------------------------------------------------------------------------
__global__ __launch_bounds__(512, 4) void flash_attn2(const bf16_t* __restrict__ q,
                                                      const bf16_t* __restrict__ k,
                                                      const bf16_t* __restrict__ vt,
                                                      const float* __restrict__ bias,
                                                      bf16_t* __restrict__ o) {
  __shared__ __align__(16) bf16_t Kbuf[2][64 * 128];   // 2 x 16 KB swizzled
  __shared__ __align__(16) bf16_t Vbuf[2][128 * 64];   // 2 x 16 KB swizzled
  __shared__ __align__(16) float  Bb[2048];            // 8 KB bias row

  const int tid  = threadIdx.x;
  const int lane = tid & 63;
  const int wave = tid >> 6;
  const int l15  = lane & 15;
  const int quad = lane >> 4;

  // 512 blocks, 2/CU: co-resident pair {i, i+256} -> c and 15-c
  // (rounds (32-c) + (17+c) = 49, balanced per CU).
  const int bi   = blockIdx.x;
  const int half = bi >> 8;
  const int jj   = bi & 255;
  const int cc   = jj >> 5;
  const int c    = half ? (15 - cc) : cc;          // 0..15
  const int bh = jj & 31;
  const int b  = bh >> 4;
  const int h  = bh & 15;
  const int kv = h >> 2;

  const int tile = (wave < 4) ? c : (31 - c);      // 64-row tile index
  const int q0   = tile * 64 + (wave & 3) * 16;    // this wave's 16-row strip
  const int nrounds = 32 - c;                      // 17..32

  bf16x8 qf[4];
  {
    const bf16_t* qb = q + ((size_t)(b * LL + q0 + l15)) * (HQ * DHD) + h * DHD + quad * 8;
#pragma unroll
    for (int t = 0; t < 4; t++) qf[t] = *(const bf16x8*)(qb + 32 * t);
  }

  f32x4 acc[8];
#pragma unroll
  for (int mt = 0; mt < 8; mt++) acc[mt] = {0.f, 0.f, 0.f, 0.f};
  float m_i = -1e30f;      // per-row (uniform across the row's 4 quads)
  float l_i = 0.f;         // LANE-PARTIAL (this quad's keys); reduced at end

  const bf16_t* kg_base = k + ((size_t)(b * LL)) * (HKV * DHD) + kv * DHD;
  const bf16_t* vg_base = vt + ((size_t)(b * HKV + kv) * DHD) * LL;
  const float*  bias_b  = bias + b * LL;

  // Bias row -> LDS (8 KB once; 512 float4 = 2048 floats).
  ((float4*)Bb)[tid] = ((const float4*)bias_b)[tid];

  // Staging split across 512 threads: K 64x128 (2 chunks of 32 rows),
  // V^T 128x64 (2 chunks of 64 d-rows).
  const int krow = tid >> 4, kch = tid & 15;       // krow 0..31
  const int vrow = tid >> 3, vch = tid & 7;        // vrow 0..63
  // V column permutation for the low half of a bf16x8 global chunk at vch:
  // keys 8*vch+m -> col c(k); high half lands at +8 elems (+16 bytes).
  const int vc0  = ((vch >> 2) << 5) + (((vch << 1) & 3) << 3) + (((vch >> 1) & 1) << 2);
  const int vblo = vc0 * 2;                 // byte offset in 128B row
  const int ksw  = (krow & 7) << 4;         // row&7 preserved by +32 chunks
  const int vsw  = (vrow & 7) << 4;         // row&7 preserved by +64 chunks
  const int rsw  = (l15 & 7) << 4;          // read-side swizzle (row = *16+l15)

  const bf16_t* kg0 = kg_base + (size_t)krow * (HKV * DHD) + kch * 8;
  const bf16_t* vg0 = vg_base + (size_t)vrow * LL + vch * 8;

  bf16x8 kl[2], vl[2];
  auto ISSUE = [&](int j0) {
#pragma unroll
    for (int p = 0; p < 2; p++)
      kl[p] = *(const bf16x8*)(kg0 + (size_t)(j0 + p * 32) * (HKV * DHD));
#pragma unroll
    for (int p = 0; p < 2; p++)
      vl[p] = *(const bf16x8*)(vg0 + j0 + (size_t)p * 64 * LL);
  };
  auto STAGE = [&](int bsel) {
    char* kb = (char*)(&Kbuf[bsel][0]);
    char* vb = (char*)(&Vbuf[bsel][0]);
#pragma unroll
    for (int p = 0; p < 2; p++)
      *(bf16x8*)(kb + (size_t)(krow + p * 32) * 256 + ((kch * 16) ^ ksw)) = kl[p];
#pragma unroll
    for (int p = 0; p < 2; p++) {
      char* vbase = vb + (size_t)(vrow + p * 64) * 128;
      bf16x4 lo4 = __builtin_shufflevector(vl[p], vl[p], 0, 1, 2, 3);
      bf16x4 hi4 = __builtin_shufflevector(vl[p], vl[p], 4, 5, 6, 7);
      *(bf16x4*)(vbase + (vblo ^ vsw)) = lo4;
      *(bf16x4*)(vbase + ((vblo + 16) ^ vsw)) = hi4;
    }
  };

  // Prologue: stage round 0 into buf0.
  ISSUE(0);
  STAGE(0);
  __syncthreads();

  int cur = 0;
  for (int r = 0; r < nrounds; r++) {
    const int j0 = r * 64;
    const bool last = (r + 1 >= nrounds);
    if (!last) ISSUE(j0 + 64);   // issue-early: lands during compute (T14)

    const bool act = (j0 <= q0 + 15);   // wave-uniform
    if (act) {
      const char* KbC = (const char*)(&Kbuf[cur][0]);
      const char* VbC = (const char*)(&Vbuf[cur][0]);

      // ---- QK^T (S^T): A = K row, B = Q^T; D row = key (quad*4+i), col = qrow.
      f32x4 s[4];
      __builtin_amdgcn_s_setprio(1);
#pragma unroll
      for (int kt = 0; kt < 4; kt++) {
        const char* kr = KbC + (size_t)(kt * 16 + l15) * 256;
        f32x4 s0 = {0.f, 0.f, 0.f, 0.f};
#pragma unroll
        for (int t = 0; t < 4; t++) {
          bf16x8 kf = *(const bf16x8*)(kr + ((quad * 16 + t * 64) ^ rsw));
          s0 = mfma16(kf, qf[t], s0);
        }
        s[kt] = s0;
      }
      __builtin_amdgcn_s_setprio(0);

      // ---- online softmax in log2 domain (Q pre-scaled by QSC). P stays in
      //      registers: lane's p4 per kt IS the K=16 B-frag for PV.
      const int qrow = q0 + l15;
      const bool diag = (j0 + 63 > q0);      // mask iff max key > min row
      float mx = -1e30f;                     // per-lane partial max
#pragma unroll
      for (int kt = 0; kt < 4; kt++) {
        f32x4 sv = s[kt];
        f32x4 bv = *(const f32x4*)(&Bb[j0 + kt * 16 + quad * 4]);
#pragma unroll
        for (int i = 0; i < 4; i++) {
          float x = sv[i] + bv[i];
          if (diag) {
            int key = j0 + kt * 16 + quad * 4 + i;
            if (key > qrow) x = MINV;
          }
          sv[i] = x;
          mx = fmaxf(mx, x);
        }
        s[kt] = sv;
      }
      // defer-max (T13) with PER-LANE partial max: __all() reduces across the
      // wave, so this is equivalent to checking the row-reduced max. The two
      // max-shuffles only run on the rare rescale path.
      if (!__all(mx <= m_i + 8.0f)) {
        mx = fmaxf(mx, __shfl_xor(mx, 16));
        mx = fmaxf(mx, __shfl_xor(mx, 32));   // now per-row max
        const float mn = fmaxf(m_i, mx);
        const float alpha = EXP2F(m_i - mn);
        m_i = mn;
        l_i *= alpha;
#pragma unroll
        for (int mt = 0; mt < 8; mt++) {
          acc[mt][0] *= alpha; acc[mt][1] *= alpha;
          acc[mt][2] *= alpha; acc[mt][3] *= alpha;
        }
      }
      const float mn = m_i;
      float sum = 0.f;
      bf16x4 pf[4];
#pragma unroll
      for (int kt = 0; kt < 4; kt++) {
        f32x4 sv = s[kt];
        bf16x4 p4;
#pragma unroll
        for (int i = 0; i < 4; i++) {
          float pe = EXP2F(sv[i] - mn);
          sum += pe;
          p4[i] = (bf16_t)pe;
        }
        pf[kt] = p4;
      }
      l_i += sum;    // lane-partial; cross-quad reduce deferred to epilogue

      // ---- PV with K=16 MFMA: A = V^T frag (k=quad*4+j via permuted cols),
      //      B = pf (lane-local). acc layout: row=d (mt*16+quad*4+i), col=qrow.
      __builtin_amdgcn_s_setprio(1);
#pragma unroll
      for (int mt = 0; mt < 8; mt++) {
        const char* vr = VbC + (size_t)(mt * 16 + l15) * 128;
        bf16x8 v01 = *(const bf16x8*)(vr + ((quad * 16) ^ rsw));
        bf16x8 v23 = *(const bf16x8*)(vr + ((64 + quad * 16) ^ rsw));
        bf16x4 va = __builtin_shufflevector(v01, v01, 0, 1, 2, 3);
        bf16x4 vb = __builtin_shufflevector(v01, v01, 4, 5, 6, 7);
        bf16x4 vc = __builtin_shufflevector(v23, v23, 0, 1, 2, 3);
        bf16x4 vd = __builtin_shufflevector(v23, v23, 4, 5, 6, 7);
        acc[mt] = mfma16k16(va, pf[0], acc[mt]);
        acc[mt] = mfma16k16(vb, pf[1], acc[mt]);
        acc[mt] = mfma16k16(vc, pf[2], acc[mt]);
        acc[mt] = mfma16k16(vd, pf[3], acc[mt]);
      }
      __builtin_amdgcn_s_setprio(0);
    }

    // ---- stage round r+1 into the other buffer; single barrier per round.
    if (!last) {
      STAGE(cur ^ 1);
      __syncthreads();
      cur ^= 1;
    }
  }

  {
    // Epilogue: reduce the lane-partial l_i across the row's 4 quads (once).
    l_i += __shfl_xor(l_i, 16);
    l_i += __shfl_xor(l_i, 32);
    const float invl = 1.0f / l_i;
    bf16_t* ob = o + ((size_t)(b * LL + q0 + l15)) * (HQ * DHD) + h * DHD + quad * 4;
#pragma unroll
    for (int mt = 0; mt < 8; mt++) {
      f32x4 a = acc[mt];
      bf16x4 w = {(bf16_t)(a[0] * invl), (bf16_t)(a[1] * invl),
                  (bf16_t)(a[2] * invl), (bf16_t)(a[3] * invl)};
      *(bf16x4*)(ob + mt * 16) = w;
    }
  }
}

extern "C" void kernel_launch(void* const* d_in, const int* in_sizes, int n_in,
                              void* d_out, int out_size, void* d_ws, size_t ws_size,
                              hipStream_t stream) {
  const float* hidden = (const float*)d_in[0];
  const int*   amask  = (const int*)d_in[1];
  const float* Wq     = (const float*)d_in[2];
  const float* Wk     = (const float*)d_in[3];
  const float* Wv     = (const float*)d_in[4];
  const float* Wo     = (const float*)d_in[5];
  float* out = (float*)d_out;

  const int M = BB * LL;           // 4096
  const size_t MB = 1u << 20;
  char* ws = (char*)d_ws;
  bf16_t* hid_b   = (bf16_t*)(ws);            // 16 MB  (B,L,D)
  bf16_t* q_ws    = (bf16_t*)(ws + 16 * MB);  // 16 MB
  bf16_t* attn_ws = (bf16_t*)(ws + 32 * MB);  // 16 MB
  bf16_t* k_ws    = (bf16_t*)(ws + 48 * MB);  //  4 MB
  bf16_t* vt_ws   = (bf16_t*)(ws + 52 * MB);  //  4 MB
  bf16_t* wqkv_b  = (bf16_t*)(ws + 56 * MB);  // 12 MB: Wq(8) + Wk(2) + Wv(2)
  bf16_t* wq_b    = wqkv_b;
  bf16_t* wk_b    = (bf16_t*)(ws + 64 * MB);
  bf16_t* wv_b    = (bf16_t*)(ws + 66 * MB);
  bf16_t* wo_b    = (bf16_t*)(ws + 68 * MB);  //  8 MB
  float*  bias_ws = (float*)(ws);             // 16 KB, aliases hid_b

  CastArgs ca;
  ca.s[0] = hidden; ca.d[0] = hid_b; ca.n[0] = BB * LL * DDIM;
  ca.s[1] = Wq;     ca.d[1] = wq_b;  ca.n[1] = HQ * DHD * DDIM;
  ca.s[2] = Wk;     ca.d[2] = wk_b;  ca.n[2] = HKV * DHD * DDIM;
  ca.s[3] = Wv;     ca.d[3] = wv_b;  ca.n[3] = HKV * DHD * DDIM;
  ca.s[4] = Wo;     ca.d[4] = wo_b;  ca.n[4] = DDIM * DDIM;
  {
    int maxn = BB * LL * DDIM;
    dim3 g((maxn / 8 + 255) / 256, 5);
    cast5_kernel<<<g, 256, 0, stream>>>(ca);
  }

  gemm_tile<3><<<dim3(3072 / 128, M / 128), 256, 0, stream>>>(
      hid_b, wqkv_b, q_ws, k_ws, vt_ws, M, 3072, DDIM);

  {
    int total = BB * LL * (HQ + HKV) * 64 + BB * LL;
    rope_kernel<<<(total + 255) / 256, 256, 0, stream>>>(q_ws, k_ws, amask, bias_ws);
  }

  flash_attn2<<<512, 512, 0, stream>>>(q_ws, k_ws, vt_ws, bias_ws, attn_ws);

  gemm_tile<2><<<dim3(DDIM / 128, M / 128), 256, 0, stream>>>(
      attn_ws, wo_b, (void*)out, nullptr, nullptr, M, DDIM, DDIM);
}

// Round 7
// 307.099 us; speedup vs baseline: 1.0793x; 1.0045x over previous
//
#include <hip/hip_runtime.h>
#include <cstdint>
#include <cmath>

// ---------------------------------------------------------------------------
// LlamaAttention round 14: fuse RoPE into the QKV epilogue; bias into flash.
//   B=2 L=2048 D=2048 H=16 KV=4 DH=128, causal + key-padding mask, RoPE.
// R13 POST-MORTEM: GEMM revert confirmed (QKV 77us, conflicts 6.3M); flash
//   de-shuffle confirmed (~70us, below top-5 cutoff). 5-kernel pipeline:
//   rope (~8us + launch gap) re-reads/writes 40MB that the QKV epilogue
//   already holds in registers -- each 128-col tile is exactly one head, so
//   the (d,d+64) RoPE partner is in the SAME block, neighboring wave pair.
// R14:
//   1. rope_kernel deleted. gemm_tile<3> epilogue: for q/k tiles, wave pairs
//      (wn=0 <-> wn=64) exchange 16-row slices via 32KB LDS (8 barriers,
//      once per block), inline __sincosf (same math as old kernel), apply
//      rotation (+QSC for q), store. v tiles unchanged.
//   2. flash builds Bb from amask directly (int4 read), bias_ws deleted.
// Pipeline: cast5 -> QKV(+RoPE) -> flash -> O-proj (4 kernels).
// MFMA layouts (learn_hip m89/m91): A[m=l15][k], B[k][n=l15],
//   C/D: col=l15, row=quad*4+reg (shape-determined).
// ---------------------------------------------------------------------------

typedef __bf16 bf16_t;
typedef __bf16 bf16x8 __attribute__((ext_vector_type(8)));
typedef __bf16 bf16x4 __attribute__((ext_vector_type(4)));
typedef float  f32x4  __attribute__((ext_vector_type(4)));

#define HQ   16
#define HKV  4
#define GQA  4
#define DHD  128
#define BB   2
#define LL   2048
#define DDIM 2048
#define MINV (-1e15f)
// 1/sqrt(128) * log2(e): folded into Q at epilogue time so flash uses exp2.
#define QSC  0.12751744f

static __device__ __forceinline__ f32x4 mfma16(bf16x8 a, bf16x8 b, f32x4 c) {
  return __builtin_amdgcn_mfma_f32_16x16x32_bf16(a, b, c, 0, 0, 0);
}

// K=16 bf16 MFMA (PV step): A/B are 4 bf16 per lane, k = quad*4+j.
static __device__ __forceinline__ f32x4 mfma16k16(bf16x4 a, bf16x4 b, f32x4 c) {
#if __has_builtin(__builtin_amdgcn_mfma_f32_16x16x16bf16_1k)
  typedef short s4 __attribute__((ext_vector_type(4)));
  union U { bf16x4 h; s4 s; };
  U ua, ub; ua.h = a; ub.h = b;
  return __builtin_amdgcn_mfma_f32_16x16x16bf16_1k(ua.s, ub.s, c, 0, 0, 0);
#elif __has_builtin(__builtin_amdgcn_mfma_f32_16x16x16_bf16)
  return __builtin_amdgcn_mfma_f32_16x16x16_bf16(a, b, c, 0, 0, 0);
#else
  f32x4 d;
  asm volatile("v_mfma_f32_16x16x16_bf16 %0, %1, %2, %3"
               : "=v"(d) : "v"(a), "v"(b), "v"(c));
  return d;
#endif
}

#if __has_builtin(__builtin_amdgcn_exp2f)
#define EXP2F(x) __builtin_amdgcn_exp2f(x)
#else
#define EXP2F(x) exp2f(x)
#endif

static __device__ __forceinline__ void gld16(const bf16_t* g, bf16_t* l) {
  __builtin_amdgcn_global_load_lds(
      (const __attribute__((address_space(1))) void*)g,
      (__attribute__((address_space(3))) void*)l,
      16, 0, 0);
}

// ---------------- f32 -> bf16 cast (5 tensors in one launch) ----------------
struct CastArgs {
  const float* s[5];
  bf16_t* d[5];
  int n[5];
};

__global__ __launch_bounds__(256) void cast5_kernel(CastArgs a) {
  const int t = blockIdx.y;
  const int i8 = (blockIdx.x * 256 + threadIdx.x) * 8;
  if (i8 >= a.n[t]) return;
  const float4* s = (const float4*)(a.s[t] + i8);
  float4 x = s[0], y = s[1];
  bf16x8 o = {(bf16_t)x.x, (bf16_t)x.y, (bf16_t)x.z, (bf16_t)x.w,
              (bf16_t)y.x, (bf16_t)y.y, (bf16_t)y.z, (bf16_t)y.w};
  *(bf16x8*)(a.d[t] + i8) = o;
}

// ---------------------------------------------------------------------------
// Tiled GEMM: C = A(MxK) * W(NxK)^T, 128x128 tile, BK=32 (m97 structure).
// STORE 2: f32 row-major -> C0.
// STORE 3: fused QKV epilogue (N=3072) WITH IN-EPILOGUE RoPE:
//   cols [0,2048): q -> C0 bf16 row-major, RoPE'd + QSC-scaled.
//   cols [2048,2560): k -> Ck bf16 row-major (N=512), RoPE'd.
//   cols [2560,3072): v -> Cv transposed (B,KV,DH,L), bf16x4 along L.
//   RoPE exchange: each 128-col tile is one head; wave pair (wn=0, wn=64)
//   holds (d, d+64). Exchange 16-row mi-slices via Ex (32KB LDS), 2 barriers
//   per slice. Angle/trig math identical to the old rope_kernel.
// ---------------------------------------------------------------------------
template <int STORE>
__global__ __launch_bounds__(256) void gemm_tile(const bf16_t* __restrict__ A,
                                                 const bf16_t* __restrict__ W,
                                                 void* __restrict__ C0,
                                                 bf16_t* __restrict__ Ck,
                                                 bf16_t* __restrict__ Cv,
                                                 int M, int N, int K) {
  __shared__ __align__(16) bf16_t As[128 * 32];
  __shared__ __align__(16) bf16_t Bs[128 * 32];
  __shared__ float Ex[(STORE == 3) ? (4 * 16 * 128) : 4];  // 32KB exchange
  const int tid  = threadIdx.x;
  const int lane = tid & 63;
  const int wave = tid >> 6;
  const int l15  = lane & 15;
  const int quad = lane >> 4;
  const int m0 = blockIdx.y * 128;
  const int n0 = blockIdx.x * 128;

  const int srow = wave * 32 + (lane >> 2);
  const int scol = (lane & 3) * 8;
  const bf16_t* ag = A + (size_t)(m0 + srow) * K + scol;
  const bf16_t* wg = W + (size_t)(n0 + srow) * K + scol;
  bf16_t* al = As + wave * 1024;
  bf16_t* bl = Bs + wave * 1024;

  const int wm = (wave >> 1) * 64;
  const int wn = (wave & 1) * 64;

  f32x4 acc[4][4];
#pragma unroll
  for (int mi = 0; mi < 4; mi++)
#pragma unroll
    for (int ni = 0; ni < 4; ni++) acc[mi][ni] = {0.f, 0.f, 0.f, 0.f};

  for (int k0 = 0; k0 < K; k0 += 32) {
    __syncthreads();
    gld16(ag + k0, al);
    gld16(ag + k0 + (size_t)16 * K, al + 512);
    gld16(wg + k0, bl);
    gld16(wg + k0 + (size_t)16 * K, bl + 512);
    __syncthreads();
    bf16x8 af[4], bfr[4];
#pragma unroll
    for (int mi = 0; mi < 4; mi++)
      af[mi] = *(const bf16x8*)(As + (wm + mi * 16 + l15) * 32 + quad * 8);
#pragma unroll
    for (int ni = 0; ni < 4; ni++)
      bfr[ni] = *(const bf16x8*)(Bs + (wn + ni * 16 + l15) * 32 + quad * 8);
#pragma unroll
    for (int mi = 0; mi < 4; mi++)
#pragma unroll
      for (int ni = 0; ni < 4; ni++)
        acc[mi][ni] = mfma16(af[mi], bfr[ni], acc[mi][ni]);
  }

  if (STORE == 2) {
    float* C = (float*)C0;
#pragma unroll
    for (int mi = 0; mi < 4; mi++) {
      const int row = m0 + wm + mi * 16 + quad * 4;
#pragma unroll
      for (int ni = 0; ni < 4; ni++) {
        const int col = n0 + wn + ni * 16 + l15;
#pragma unroll
        for (int i = 0; i < 4; i++)
          C[(size_t)(row + i) * N + col] = acc[mi][ni][i];
      }
    }
  } else {  // STORE == 3
    if (n0 < 2560) {
      // q or k tile: fused RoPE with cross-wave (d, d+64) exchange.
      const bool isq = (n0 < 2048);
      const int pair = wave >> 1;
      float* exw = Ex + (pair * 16 + quad * 4) * 128 + wn + l15;
      const float* exr = Ex + (pair * 16 + quad * 4) * 128 + (wn ^ 64) + l15;
#pragma unroll
      for (int mi = 0; mi < 4; mi++) {
        __syncthreads();     // Ex free (previous slice's reads done)
#pragma unroll
        for (int ni = 0; ni < 4; ni++)
#pragma unroll
          for (int i = 0; i < 4; i++)
            exw[i * 128 + ni * 16] = acc[mi][ni][i];
        __syncthreads();
        const int row = m0 + wm + mi * 16 + quad * 4;
#pragma unroll
        for (int ni = 0; ni < 4; ni++) {
          const int dl = ni * 16 + l15;     // low-half head dim (0..63)
          // invf = 10000^(-dl/64)  (identical math to old rope_kernel)
          const float invf = __expf(-(float)dl * 0.14391156862532788f);
#pragma unroll
          for (int i = 0; i < 4; i++) {
            const int l = (row + i) & (LL - 1);
            float sn, cs;
            __sincosf((float)l * invf, &sn, &cs);
            const float own = acc[mi][ni][i];
            const float oth = exr[i * 128 + ni * 16];
            // wn==0 lane holds x1 (d<64): out = x1*c - x2*s
            // wn==64 lane holds x2:       out = x2*c + x1*s
            const float out = (wn == 0) ? (own * cs - oth * sn)
                                        : (own * cs + oth * sn);
            if (isq) {
              ((bf16_t*)C0)[(size_t)(row + i) * 2048 + (n0 + wn + dl)] =
                  (bf16_t)(out * QSC);
            } else {
              Ck[(size_t)(row + i) * 512 + (n0 - 2048 + wn + dl)] =
                  (bf16_t)out;
            }
          }
        }
      }
    } else {
      // v tile: transposed store, no RoPE.
#pragma unroll
      for (int mi = 0; mi < 4; mi++) {
        const int row = m0 + wm + mi * 16 + quad * 4;
        const int b = row >> 11;
        const int l0 = row & (LL - 1);
#pragma unroll
        for (int ni = 0; ni < 4; ni++) {
          const int kvcol = n0 - 2560 + wn + ni * 16 + l15;
          const int kvh = kvcol >> 7, d = kvcol & 127;
          bf16x4 w4 = {(bf16_t)acc[mi][ni][0], (bf16_t)acc[mi][ni][1],
                       (bf16_t)acc[mi][ni][2], (bf16_t)acc[mi][ni][3]};
          *(bf16x4*)(Cv + ((size_t)(b * HKV + kvh) * DHD + d) * LL + l0) = w4;
        }
      }
    }
  }
}

// ---------------------------------------------------------------------------
// Flash attention: 512 blocks x 512 threads (8 waves). Block owns 128-row
// tile pair {c, 31-c}: waves 0-3 -> tile c (16-row strips), waves 4-7 ->
// tile 31-c. KV round = 64 keys, double-buffered LDS, 1 barrier/round.
// Kbuf[key 0..63][d 0..127] bf16, row 256B, byte ^= (row&7)<<4 swizzle.
// Vbuf[d 0..127][key-col 0..63] bf16, row 128B, same swizzle, with column
// permutation so a b128 read at col kt2*32+quad*8 yields K=16 A-frags for
// kt=2*kt2, 2*kt2+1. P register-resident (S^T lane layout = K=16 B-frag).
// Round r: issue loads r+1 -> compute buf[cur] -> write buf[cur^1] -> sync.
// Softmax common path has no cross-lane ops (per-lane defer check;
// lane-partial l_i reduced once in the epilogue); setprio around MFMA.
// R14: Bb built from amask directly (int4), bias workspace removed.
// ---------------------------------------------------------------------------
__global__ __launch_bounds__(512, 4) void flash_attn2(const bf16_t* __restrict__ q,
                                                      const bf16_t* __restrict__ k,
                                                      const bf16_t* __restrict__ vt,
                                                      const int* __restrict__ amask,
                                                      bf16_t* __restrict__ o) {
  __shared__ __align__(16) bf16_t Kbuf[2][64 * 128];   // 2 x 16 KB swizzled
  __shared__ __align__(16) bf16_t Vbuf[2][128 * 64];   // 2 x 16 KB swizzled
  __shared__ __align__(16) float  Bb[2048];            // 8 KB bias row

  const int tid  = threadIdx.x;
  const int lane = tid & 63;
  const int wave = tid >> 6;
  const int l15  = lane & 15;
  const int quad = lane >> 4;

  // 512 blocks, 2/CU: co-resident pair {i, i+256} -> c and 15-c
  // (rounds (32-c) + (17+c) = 49, balanced per CU).
  const int bi   = blockIdx.x;
  const int half = bi >> 8;
  const int jj   = bi & 255;
  const int cc   = jj >> 5;
  const int c    = half ? (15 - cc) : cc;          // 0..15
  const int bh = jj & 31;
  const int b  = bh >> 4;
  const int h  = bh & 15;
  const int kv = h >> 2;

  const int tile = (wave < 4) ? c : (31 - c);      // 64-row tile index
  const int q0   = tile * 64 + (wave & 3) * 16;    // this wave's 16-row strip
  const int nrounds = 32 - c;                      // 17..32

  bf16x8 qf[4];
  {
    const bf16_t* qb = q + ((size_t)(b * LL + q0 + l15)) * (HQ * DHD) + h * DHD + quad * 8;
#pragma unroll
    for (int t = 0; t < 4; t++) qf[t] = *(const bf16x8*)(qb + 32 * t);
  }

  f32x4 acc[8];
#pragma unroll
  for (int mt = 0; mt < 8; mt++) acc[mt] = {0.f, 0.f, 0.f, 0.f};
  float m_i = -1e30f;      // per-row (uniform across the row's 4 quads)
  float l_i = 0.f;         // LANE-PARTIAL (this quad's keys); reduced at end

  const bf16_t* kg_base = k + ((size_t)(b * LL)) * (HKV * DHD) + kv * DHD;
  const bf16_t* vg_base = vt + ((size_t)(b * HKV + kv) * DHD) * LL;

  // Bias row from amask -> LDS (once; 512 threads x int4 = 2048 entries).
  {
    int4 am = ((const int4*)(amask + b * LL))[tid];
    f32x4 bv = { am.x ? 0.f : MINV, am.y ? 0.f : MINV,
                 am.z ? 0.f : MINV, am.w ? 0.f : MINV };
    ((f32x4*)Bb)[tid] = bv;
  }

  // Staging split across 512 threads: K 64x128 (2 chunks of 32 rows),
  // V^T 128x64 (2 chunks of 64 d-rows).
  const int krow = tid >> 4, kch = tid & 15;       // krow 0..31
  const int vrow = tid >> 3, vch = tid & 7;        // vrow 0..63
  // V column permutation for the low half of a bf16x8 global chunk at vch:
  // keys 8*vch+m -> col c(k); high half lands at +8 elems (+16 bytes).
  const int vc0  = ((vch >> 2) << 5) + (((vch << 1) & 3) << 3) + (((vch >> 1) & 1) << 2);
  const int vblo = vc0 * 2;                 // byte offset in 128B row
  const int ksw  = (krow & 7) << 4;         // row&7 preserved by +32 chunks
  const int vsw  = (vrow & 7) << 4;         // row&7 preserved by +64 chunks
  const int rsw  = (l15 & 7) << 4;          // read-side swizzle (row = *16+l15)

  const bf16_t* kg0 = kg_base + (size_t)krow * (HKV * DHD) + kch * 8;
  const bf16_t* vg0 = vg_base + (size_t)vrow * LL + vch * 8;

  bf16x8 kl[2], vl[2];
  auto ISSUE = [&](int j0) {
#pragma unroll
    for (int p = 0; p < 2; p++)
      kl[p] = *(const bf16x8*)(kg0 + (size_t)(j0 + p * 32) * (HKV * DHD));
#pragma unroll
    for (int p = 0; p < 2; p++)
      vl[p] = *(const bf16x8*)(vg0 + j0 + (size_t)p * 64 * LL);
  };
  auto STAGE = [&](int bsel) {
    char* kb = (char*)(&Kbuf[bsel][0]);
    char* vb = (char*)(&Vbuf[bsel][0]);
#pragma unroll
    for (int p = 0; p < 2; p++)
      *(bf16x8*)(kb + (size_t)(krow + p * 32) * 256 + ((kch * 16) ^ ksw)) = kl[p];
#pragma unroll
    for (int p = 0; p < 2; p++) {
      char* vbase = vb + (size_t)(vrow + p * 64) * 128;
      bf16x4 lo4 = __builtin_shufflevector(vl[p], vl[p], 0, 1, 2, 3);
      bf16x4 hi4 = __builtin_shufflevector(vl[p], vl[p], 4, 5, 6, 7);
      *(bf16x4*)(vbase + (vblo ^ vsw)) = lo4;
      *(bf16x4*)(vbase + ((vblo + 16) ^ vsw)) = hi4;
    }
  };

  // Prologue: stage round 0 into buf0.
  ISSUE(0);
  STAGE(0);
  __syncthreads();

  int cur = 0;
  for (int r = 0; r < nrounds; r++) {
    const int j0 = r * 64;
    const bool last = (r + 1 >= nrounds);
    if (!last) ISSUE(j0 + 64);   // issue-early: lands during compute (T14)

    const bool act = (j0 <= q0 + 15);   // wave-uniform
    if (act) {
      const char* KbC = (const char*)(&Kbuf[cur][0]);
      const char* VbC = (const char*)(&Vbuf[cur][0]);

      // ---- QK^T (S^T): A = K row, B = Q^T; D row = key (quad*4+i), col = qrow.
      f32x4 s[4];
      __builtin_amdgcn_s_setprio(1);
#pragma unroll
      for (int kt = 0; kt < 4; kt++) {
        const char* kr = KbC + (size_t)(kt * 16 + l15) * 256;
        f32x4 s0 = {0.f, 0.f, 0.f, 0.f};
#pragma unroll
        for (int t = 0; t < 4; t++) {
          bf16x8 kf = *(const bf16x8*)(kr + ((quad * 16 + t * 64) ^ rsw));
          s0 = mfma16(kf, qf[t], s0);
        }
        s[kt] = s0;
      }
      __builtin_amdgcn_s_setprio(0);

      // ---- online softmax in log2 domain (Q pre-scaled by QSC). P stays in
      //      registers: lane's p4 per kt IS the K=16 B-frag for PV.
      const int qrow = q0 + l15;
      const bool diag = (j0 + 63 > q0);      // mask iff max key > min row
      float mx = -1e30f;                     // per-lane partial max
#pragma unroll
      for (int kt = 0; kt < 4; kt++) {
        f32x4 sv = s[kt];
        f32x4 bv = *(const f32x4*)(&Bb[j0 + kt * 16 + quad * 4]);
#pragma unroll
        for (int i = 0; i < 4; i++) {
          float x = sv[i] + bv[i];
          if (diag) {
            int key = j0 + kt * 16 + quad * 4 + i;
            if (key > qrow) x = MINV;
          }
          sv[i] = x;
          mx = fmaxf(mx, x);
        }
        s[kt] = sv;
      }
      // defer-max (T13) with PER-LANE partial max: __all() reduces across the
      // wave, so this is equivalent to checking the row-reduced max. The two
      // max-shuffles only run on the rare rescale path.
      if (!__all(mx <= m_i + 8.0f)) {
        mx = fmaxf(mx, __shfl_xor(mx, 16));
        mx = fmaxf(mx, __shfl_xor(mx, 32));   // now per-row max
        const float mn = fmaxf(m_i, mx);
        const float alpha = EXP2F(m_i - mn);
        m_i = mn;
        l_i *= alpha;
#pragma unroll
        for (int mt = 0; mt < 8; mt++) {
          acc[mt][0] *= alpha; acc[mt][1] *= alpha;
          acc[mt][2] *= alpha; acc[mt][3] *= alpha;
        }
      }
      const float mn = m_i;
      float sum = 0.f;
      bf16x4 pf[4];
#pragma unroll
      for (int kt = 0; kt < 4; kt++) {
        f32x4 sv = s[kt];
        bf16x4 p4;
#pragma unroll
        for (int i = 0; i < 4; i++) {
          float pe = EXP2F(sv[i] - mn);
          sum += pe;
          p4[i] = (bf16_t)pe;
        }
        pf[kt] = p4;
      }
      l_i += sum;    // lane-partial; cross-quad reduce deferred to epilogue

      // ---- PV with K=16 MFMA: A = V^T frag (k=quad*4+j via permuted cols),
      //      B = pf (lane-local). acc layout: row=d (mt*16+quad*4+i), col=qrow.
      __builtin_amdgcn_s_setprio(1);
#pragma unroll
      for (int mt = 0; mt < 8; mt++) {
        const char* vr = VbC + (size_t)(mt * 16 + l15) * 128;
        bf16x8 v01 = *(const bf16x8*)(vr + ((quad * 16) ^ rsw));
        bf16x8 v23 = *(const bf16x8*)(vr + ((64 + quad * 16) ^ rsw));
        bf16x4 va = __builtin_shufflevector(v01, v01, 0, 1, 2, 3);
        bf16x4 vb = __builtin_shufflevector(v01, v01, 4, 5, 6, 7);
        bf16x4 vc = __builtin_shufflevector(v23, v23, 0, 1, 2, 3);
        bf16x4 vd = __builtin_shufflevector(v23, v23, 4, 5, 6, 7);
        acc[mt] = mfma16k16(va, pf[0], acc[mt]);
        acc[mt] = mfma16k16(vb, pf[1], acc[mt]);
        acc[mt] = mfma16k16(vc, pf[2], acc[mt]);
        acc[mt] = mfma16k16(vd, pf[3], acc[mt]);
      }
      __builtin_amdgcn_s_setprio(0);
    }

    // ---- stage round r+1 into the other buffer; single barrier per round.
    if (!last) {
      STAGE(cur ^ 1);
      __syncthreads();
      cur ^= 1;
    }
  }

  {
    // Epilogue: reduce the lane-partial l_i across the row's 4 quads (once).
    l_i += __shfl_xor(l_i, 16);
    l_i += __shfl_xor(l_i, 32);
    const float invl = 1.0f / l_i;
    bf16_t* ob = o + ((size_t)(b * LL + q0 + l15)) * (HQ * DHD) + h * DHD + quad * 4;
#pragma unroll
    for (int mt = 0; mt < 8; mt++) {
      f32x4 a = acc[mt];
      bf16x4 w = {(bf16_t)(a[0] * invl), (bf16_t)(a[1] * invl),
                  (bf16_t)(a[2] * invl), (bf16_t)(a[3] * invl)};
      *(bf16x4*)(ob + mt * 16) = w;
    }
  }
}

extern "C" void kernel_launch(void* const* d_in, const int* in_sizes, int n_in,
                              void* d_out, int out_size, void* d_ws, size_t ws_size,
                              hipStream_t stream) {
  const float* hidden = (const float*)d_in[0];
  const int*   amask  = (const int*)d_in[1];
  const float* Wq     = (const float*)d_in[2];
  const float* Wk     = (const float*)d_in[3];
  const float* Wv     = (const float*)d_in[4];
  const float* Wo     = (const float*)d_in[5];
  float* out = (float*)d_out;

  const int M = BB * LL;           // 4096
  const size_t MB = 1u << 20;
  char* ws = (char*)d_ws;
  bf16_t* hid_b   = (bf16_t*)(ws);            // 16 MB  (B,L,D)
  bf16_t* q_ws    = (bf16_t*)(ws + 16 * MB);  // 16 MB
  bf16_t* attn_ws = (bf16_t*)(ws + 32 * MB);  // 16 MB
  bf16_t* k_ws    = (bf16_t*)(ws + 48 * MB);  //  4 MB
  bf16_t* vt_ws   = (bf16_t*)(ws + 52 * MB);  //  4 MB
  bf16_t* wqkv_b  = (bf16_t*)(ws + 56 * MB);  // 12 MB: Wq(8) + Wk(2) + Wv(2)
  bf16_t* wq_b    = wqkv_b;
  bf16_t* wk_b    = (bf16_t*)(ws + 64 * MB);
  bf16_t* wv_b    = (bf16_t*)(ws + 66 * MB);
  bf16_t* wo_b    = (bf16_t*)(ws + 68 * MB);  //  8 MB

  CastArgs ca;
  ca.s[0] = hidden; ca.d[0] = hid_b; ca.n[0] = BB * LL * DDIM;
  ca.s[1] = Wq;     ca.d[1] = wq_b;  ca.n[1] = HQ * DHD * DDIM;
  ca.s[2] = Wk;     ca.d[2] = wk_b;  ca.n[2] = HKV * DHD * DDIM;
  ca.s[3] = Wv;     ca.d[3] = wv_b;  ca.n[3] = HKV * DHD * DDIM;
  ca.s[4] = Wo;     ca.d[4] = wo_b;  ca.n[4] = DDIM * DDIM;
  {
    int maxn = BB * LL * DDIM;
    dim3 g((maxn / 8 + 255) / 256, 5);
    cast5_kernel<<<g, 256, 0, stream>>>(ca);
  }

  gemm_tile<3><<<dim3(3072 / 128, M / 128), 256, 0, stream>>>(
      hid_b, wqkv_b, q_ws, k_ws, vt_ws, M, 3072, DDIM);

  flash_attn2<<<512, 512, 0, stream>>>(q_ws, k_ws, vt_ws, amask, attn_ws);

  gemm_tile<2><<<dim3(DDIM / 128, M / 128), 256, 0, stream>>>(
      attn_ws, wo_b, (void*)out, nullptr, nullptr, M, DDIM, DDIM);
}

// Round 8
// 298.378 us; speedup vs baseline: 1.1108x; 1.0292x over previous
//
#include <hip/hip_runtime.h>
#include <cstdint>
#include <cmath>

// ---------------------------------------------------------------------------
// LlamaAttention round 15: thread-local RoPE pairs in the QKV epilogue.
//   B=2 L=2048 D=2048 H=16 KV=4 DH=128, causal + key-padding mask, RoPE.
// R14 POST-MORTEM: RoPE fusion was a wash (-1.4us): rope kernel gone (-8)
//   but QKV 77->84 (VALUBusy 43->53%: 64 duplicated sincos/thread; Ex LDS
//   48KB occupancy notch; 8 epilogue barriers).
// R15: remap wave->column so the (d,d+64) RoPE partner is THREAD-LOCAL:
//   colof(ni) = (ni&1)*16 + (ni>>1)*64 + (wave&1)*32. Wave covers {dl,dl+64}
//   for its 32 low dims; partner of acc[mi][ni] is acc[mi][ni^2] (same lane).
//   => Ex deleted (LDS back to 16KB), 8 epilogue barriers deleted, trig
//   halved (32 sincos/thread, one per pair). B-frag reads/stores get the
//   same pure column permutation; MFMA/staging untouched.
// Pipeline: cast5 -> QKV(+RoPE) -> flash -> O-proj (4 kernels).
// MFMA layouts (learn_hip m89/m91): A[m=l15][k], B[k][n=l15],
//   C/D: col=l15, row=quad*4+reg (shape-determined).
// ---------------------------------------------------------------------------

typedef __bf16 bf16_t;
typedef __bf16 bf16x8 __attribute__((ext_vector_type(8)));
typedef __bf16 bf16x4 __attribute__((ext_vector_type(4)));
typedef float  f32x4  __attribute__((ext_vector_type(4)));

#define HQ   16
#define HKV  4
#define GQA  4
#define DHD  128
#define BB   2
#define LL   2048
#define DDIM 2048
#define MINV (-1e15f)
// 1/sqrt(128) * log2(e): folded into Q at epilogue time so flash uses exp2.
#define QSC  0.12751744f

static __device__ __forceinline__ f32x4 mfma16(bf16x8 a, bf16x8 b, f32x4 c) {
  return __builtin_amdgcn_mfma_f32_16x16x32_bf16(a, b, c, 0, 0, 0);
}

// K=16 bf16 MFMA (PV step): A/B are 4 bf16 per lane, k = quad*4+j.
static __device__ __forceinline__ f32x4 mfma16k16(bf16x4 a, bf16x4 b, f32x4 c) {
#if __has_builtin(__builtin_amdgcn_mfma_f32_16x16x16bf16_1k)
  typedef short s4 __attribute__((ext_vector_type(4)));
  union U { bf16x4 h; s4 s; };
  U ua, ub; ua.h = a; ub.h = b;
  return __builtin_amdgcn_mfma_f32_16x16x16bf16_1k(ua.s, ub.s, c, 0, 0, 0);
#elif __has_builtin(__builtin_amdgcn_mfma_f32_16x16x16_bf16)
  return __builtin_amdgcn_mfma_f32_16x16x16_bf16(a, b, c, 0, 0, 0);
#else
  f32x4 d;
  asm volatile("v_mfma_f32_16x16x16_bf16 %0, %1, %2, %3"
               : "=v"(d) : "v"(a), "v"(b), "v"(c));
  return d;
#endif
}

#if __has_builtin(__builtin_amdgcn_exp2f)
#define EXP2F(x) __builtin_amdgcn_exp2f(x)
#else
#define EXP2F(x) exp2f(x)
#endif

static __device__ __forceinline__ void gld16(const bf16_t* g, bf16_t* l) {
  __builtin_amdgcn_global_load_lds(
      (const __attribute__((address_space(1))) void*)g,
      (__attribute__((address_space(3))) void*)l,
      16, 0, 0);
}

// ---------------- f32 -> bf16 cast (5 tensors in one launch) ----------------
struct CastArgs {
  const float* s[5];
  bf16_t* d[5];
  int n[5];
};

__global__ __launch_bounds__(256) void cast5_kernel(CastArgs a) {
  const int t = blockIdx.y;
  const int i8 = (blockIdx.x * 256 + threadIdx.x) * 8;
  if (i8 >= a.n[t]) return;
  const float4* s = (const float4*)(a.s[t] + i8);
  float4 x = s[0], y = s[1];
  bf16x8 o = {(bf16_t)x.x, (bf16_t)x.y, (bf16_t)x.z, (bf16_t)x.w,
              (bf16_t)y.x, (bf16_t)y.y, (bf16_t)y.z, (bf16_t)y.w};
  *(bf16x8*)(a.d[t] + i8) = o;
}

// ---------------------------------------------------------------------------
// Tiled GEMM: C = A(MxK) * W(NxK)^T, 128x128 tile, BK=32 (m97 structure).
// Wave n-columns: colof(ni) = (ni&1)*16 + (ni>>1)*64 + (wave&1)*32 -- a pure
// permutation of the 8 16-col blocks so each wave owns {dl, dl+64} pairs.
// STORE 2: f32 row-major -> C0 (permuted store indices).
// STORE 3: fused QKV epilogue (N=3072) WITH THREAD-LOCAL RoPE:
//   cols [0,2048): q -> C0 bf16 row-major, RoPE'd + QSC-scaled.
//   cols [2048,2560): k -> Ck bf16 row-major (N=512), RoPE'd.
//   cols [2560,3072): v -> Cv transposed (B,KV,DH,L), bf16x4 along L.
//   RoPE: partner of acc[mi][ni] (dl) is acc[mi][ni^2] (dl+64), same lane;
//   one __sincosf per (dl,l) serves both halves. No LDS, no barriers.
// ---------------------------------------------------------------------------
template <int STORE>
__global__ __launch_bounds__(256) void gemm_tile(const bf16_t* __restrict__ A,
                                                 const bf16_t* __restrict__ W,
                                                 void* __restrict__ C0,
                                                 bf16_t* __restrict__ Ck,
                                                 bf16_t* __restrict__ Cv,
                                                 int M, int N, int K) {
  __shared__ __align__(16) bf16_t As[128 * 32];
  __shared__ __align__(16) bf16_t Bs[128 * 32];
  const int tid  = threadIdx.x;
  const int lane = tid & 63;
  const int wave = tid >> 6;
  const int l15  = lane & 15;
  const int quad = lane >> 4;
  const int m0 = blockIdx.y * 128;
  const int n0 = blockIdx.x * 128;

  const int srow = wave * 32 + (lane >> 2);
  const int scol = (lane & 3) * 8;
  const bf16_t* ag = A + (size_t)(m0 + srow) * K + scol;
  const bf16_t* wg = W + (size_t)(n0 + srow) * K + scol;
  bf16_t* al = As + wave * 1024;
  bf16_t* bl = Bs + wave * 1024;

  const int wm   = (wave >> 1) * 64;
  const int nsel = wave & 1;
  // colof(ni): n-offset of frag ni within the 128-col tile.
  auto colof = [&](int ni) { return ((ni & 1) << 4) + ((ni >> 1) << 6) + (nsel << 5); };

  f32x4 acc[4][4];
#pragma unroll
  for (int mi = 0; mi < 4; mi++)
#pragma unroll
    for (int ni = 0; ni < 4; ni++) acc[mi][ni] = {0.f, 0.f, 0.f, 0.f};

  for (int k0 = 0; k0 < K; k0 += 32) {
    __syncthreads();
    gld16(ag + k0, al);
    gld16(ag + k0 + (size_t)16 * K, al + 512);
    gld16(wg + k0, bl);
    gld16(wg + k0 + (size_t)16 * K, bl + 512);
    __syncthreads();
    bf16x8 af[4], bfr[4];
#pragma unroll
    for (int mi = 0; mi < 4; mi++)
      af[mi] = *(const bf16x8*)(As + (wm + mi * 16 + l15) * 32 + quad * 8);
#pragma unroll
    for (int ni = 0; ni < 4; ni++)
      bfr[ni] = *(const bf16x8*)(Bs + (colof(ni) + l15) * 32 + quad * 8);
#pragma unroll
    for (int mi = 0; mi < 4; mi++)
#pragma unroll
      for (int ni = 0; ni < 4; ni++)
        acc[mi][ni] = mfma16(af[mi], bfr[ni], acc[mi][ni]);
  }

  if (STORE == 2) {
    float* C = (float*)C0;
#pragma unroll
    for (int mi = 0; mi < 4; mi++) {
      const int row = m0 + wm + mi * 16 + quad * 4;
#pragma unroll
      for (int ni = 0; ni < 4; ni++) {
        const int col = n0 + colof(ni) + l15;
#pragma unroll
        for (int i = 0; i < 4; i++)
          C[(size_t)(row + i) * N + col] = acc[mi][ni][i];
      }
    }
  } else {  // STORE == 3
    if (n0 < 2560) {
      // q or k tile: thread-local RoPE. dl = low half dim of this lane's pair.
      const bool isq = (n0 < 2048);
#pragma unroll
      for (int mi = 0; mi < 4; mi++) {
        const int row = m0 + wm + mi * 16 + quad * 4;
#pragma unroll
        for (int ni2 = 0; ni2 < 2; ni2++) {
          const int dl = (nsel << 5) + (ni2 << 4) + l15;   // 0..63
          // invf = 10000^(-dl/64)  (identical math to old rope_kernel)
          const float invf = __expf(-(float)dl * 0.14391156862532788f);
#pragma unroll
          for (int i = 0; i < 4; i++) {
            const int l = (row + i) & (LL - 1);
            float sn, cs;
            __sincosf((float)l * invf, &sn, &cs);
            const float x1 = acc[mi][ni2][i];        // d = dl
            const float x2 = acc[mi][ni2 | 2][i];    // d = dl + 64
            const float out_lo = x1 * cs - x2 * sn;
            const float out_hi = x2 * cs + x1 * sn;
            if (isq) {
              bf16_t* base = (bf16_t*)C0 + (size_t)(row + i) * 2048 + n0;
              base[dl]      = (bf16_t)(out_lo * QSC);
              base[dl + 64] = (bf16_t)(out_hi * QSC);
            } else {
              bf16_t* base = Ck + (size_t)(row + i) * 512 + (n0 - 2048);
              base[dl]      = (bf16_t)out_lo;
              base[dl + 64] = (bf16_t)out_hi;
            }
          }
        }
      }
    } else {
      // v tile: transposed store, no RoPE (permuted col indices).
#pragma unroll
      for (int mi = 0; mi < 4; mi++) {
        const int row = m0 + wm + mi * 16 + quad * 4;
        const int b = row >> 11;
        const int l0 = row & (LL - 1);
#pragma unroll
        for (int ni = 0; ni < 4; ni++) {
          const int kvcol = n0 - 2560 + colof(ni) + l15;
          const int kvh = kvcol >> 7, d = kvcol & 127;
          bf16x4 w4 = {(bf16_t)acc[mi][ni][0], (bf16_t)acc[mi][ni][1],
                       (bf16_t)acc[mi][ni][2], (bf16_t)acc[mi][ni][3]};
          *(bf16x4*)(Cv + ((size_t)(b * HKV + kvh) * DHD + d) * LL + l0) = w4;
        }
      }
    }
  }
}

// ---------------------------------------------------------------------------
// Flash attention: 512 blocks x 512 threads (8 waves). Block owns 128-row
// tile pair {c, 31-c}: waves 0-3 -> tile c (16-row strips), waves 4-7 ->
// tile 31-c. KV round = 64 keys, double-buffered LDS, 1 barrier/round.
// Kbuf[key 0..63][d 0..127] bf16, row 256B, byte ^= (row&7)<<4 swizzle.
// Vbuf[d 0..127][key-col 0..63] bf16, row 128B, same swizzle, with column
// permutation so a b128 read at col kt2*32+quad*8 yields K=16 A-frags for
// kt=2*kt2, 2*kt2+1. P register-resident (S^T lane layout = K=16 B-frag).
// Round r: issue loads r+1 -> compute buf[cur] -> write buf[cur^1] -> sync.
// Softmax common path has no cross-lane ops (per-lane defer check;
// lane-partial l_i reduced once in the epilogue); setprio around MFMA.
// Bb built from amask directly (int4).
// ---------------------------------------------------------------------------
__global__ __launch_bounds__(512, 4) void flash_attn2(const bf16_t* __restrict__ q,
                                                      const bf16_t* __restrict__ k,
                                                      const bf16_t* __restrict__ vt,
                                                      const int* __restrict__ amask,
                                                      bf16_t* __restrict__ o) {
  __shared__ __align__(16) bf16_t Kbuf[2][64 * 128];   // 2 x 16 KB swizzled
  __shared__ __align__(16) bf16_t Vbuf[2][128 * 64];   // 2 x 16 KB swizzled
  __shared__ __align__(16) float  Bb[2048];            // 8 KB bias row

  const int tid  = threadIdx.x;
  const int lane = tid & 63;
  const int wave = tid >> 6;
  const int l15  = lane & 15;
  const int quad = lane >> 4;

  // 512 blocks, 2/CU: co-resident pair {i, i+256} -> c and 15-c
  // (rounds (32-c) + (17+c) = 49, balanced per CU).
  const int bi   = blockIdx.x;
  const int half = bi >> 8;
  const int jj   = bi & 255;
  const int cc   = jj >> 5;
  const int c    = half ? (15 - cc) : cc;          // 0..15
  const int bh = jj & 31;
  const int b  = bh >> 4;
  const int h  = bh & 15;
  const int kv = h >> 2;

  const int tile = (wave < 4) ? c : (31 - c);      // 64-row tile index
  const int q0   = tile * 64 + (wave & 3) * 16;    // this wave's 16-row strip
  const int nrounds = 32 - c;                      // 17..32

  bf16x8 qf[4];
  {
    const bf16_t* qb = q + ((size_t)(b * LL + q0 + l15)) * (HQ * DHD) + h * DHD + quad * 8;
#pragma unroll
    for (int t = 0; t < 4; t++) qf[t] = *(const bf16x8*)(qb + 32 * t);
  }

  f32x4 acc[8];
#pragma unroll
  for (int mt = 0; mt < 8; mt++) acc[mt] = {0.f, 0.f, 0.f, 0.f};
  float m_i = -1e30f;      // per-row (uniform across the row's 4 quads)
  float l_i = 0.f;         // LANE-PARTIAL (this quad's keys); reduced at end

  const bf16_t* kg_base = k + ((size_t)(b * LL)) * (HKV * DHD) + kv * DHD;
  const bf16_t* vg_base = vt + ((size_t)(b * HKV + kv) * DHD) * LL;

  // Bias row from amask -> LDS (once; 512 threads x int4 = 2048 entries).
  {
    int4 am = ((const int4*)(amask + b * LL))[tid];
    f32x4 bv = { am.x ? 0.f : MINV, am.y ? 0.f : MINV,
                 am.z ? 0.f : MINV, am.w ? 0.f : MINV };
    ((f32x4*)Bb)[tid] = bv;
  }

  // Staging split across 512 threads: K 64x128 (2 chunks of 32 rows),
  // V^T 128x64 (2 chunks of 64 d-rows).
  const int krow = tid >> 4, kch = tid & 15;       // krow 0..31
  const int vrow = tid >> 3, vch = tid & 7;        // vrow 0..63
  // V column permutation for the low half of a bf16x8 global chunk at vch:
  // keys 8*vch+m -> col c(k); high half lands at +8 elems (+16 bytes).
  const int vc0  = ((vch >> 2) << 5) + (((vch << 1) & 3) << 3) + (((vch >> 1) & 1) << 2);
  const int vblo = vc0 * 2;                 // byte offset in 128B row
  const int ksw  = (krow & 7) << 4;         // row&7 preserved by +32 chunks
  const int vsw  = (vrow & 7) << 4;         // row&7 preserved by +64 chunks
  const int rsw  = (l15 & 7) << 4;          // read-side swizzle (row = *16+l15)

  const bf16_t* kg0 = kg_base + (size_t)krow * (HKV * DHD) + kch * 8;
  const bf16_t* vg0 = vg_base + (size_t)vrow * LL + vch * 8;

  bf16x8 kl[2], vl[2];
  auto ISSUE = [&](int j0) {
#pragma unroll
    for (int p = 0; p < 2; p++)
      kl[p] = *(const bf16x8*)(kg0 + (size_t)(j0 + p * 32) * (HKV * DHD));
#pragma unroll
    for (int p = 0; p < 2; p++)
      vl[p] = *(const bf16x8*)(vg0 + j0 + (size_t)p * 64 * LL);
  };
  auto STAGE = [&](int bsel) {
    char* kb = (char*)(&Kbuf[bsel][0]);
    char* vb = (char*)(&Vbuf[bsel][0]);
#pragma unroll
    for (int p = 0; p < 2; p++)
      *(bf16x8*)(kb + (size_t)(krow + p * 32) * 256 + ((kch * 16) ^ ksw)) = kl[p];
#pragma unroll
    for (int p = 0; p < 2; p++) {
      char* vbase = vb + (size_t)(vrow + p * 64) * 128;
      bf16x4 lo4 = __builtin_shufflevector(vl[p], vl[p], 0, 1, 2, 3);
      bf16x4 hi4 = __builtin_shufflevector(vl[p], vl[p], 4, 5, 6, 7);
      *(bf16x4*)(vbase + (vblo ^ vsw)) = lo4;
      *(bf16x4*)(vbase + ((vblo + 16) ^ vsw)) = hi4;
    }
  };

  // Prologue: stage round 0 into buf0.
  ISSUE(0);
  STAGE(0);
  __syncthreads();

  int cur = 0;
  for (int r = 0; r < nrounds; r++) {
    const int j0 = r * 64;
    const bool last = (r + 1 >= nrounds);
    if (!last) ISSUE(j0 + 64);   // issue-early: lands during compute (T14)

    const bool act = (j0 <= q0 + 15);   // wave-uniform
    if (act) {
      const char* KbC = (const char*)(&Kbuf[cur][0]);
      const char* VbC = (const char*)(&Vbuf[cur][0]);

      // ---- QK^T (S^T): A = K row, B = Q^T; D row = key (quad*4+i), col = qrow.
      f32x4 s[4];
      __builtin_amdgcn_s_setprio(1);
#pragma unroll
      for (int kt = 0; kt < 4; kt++) {
        const char* kr = KbC + (size_t)(kt * 16 + l15) * 256;
        f32x4 s0 = {0.f, 0.f, 0.f, 0.f};
#pragma unroll
        for (int t = 0; t < 4; t++) {
          bf16x8 kf = *(const bf16x8*)(kr + ((quad * 16 + t * 64) ^ rsw));
          s0 = mfma16(kf, qf[t], s0);
        }
        s[kt] = s0;
      }
      __builtin_amdgcn_s_setprio(0);

      // ---- online softmax in log2 domain (Q pre-scaled by QSC). P stays in
      //      registers: lane's p4 per kt IS the K=16 B-frag for PV.
      const int qrow = q0 + l15;
      const bool diag = (j0 + 63 > q0);      // mask iff max key > min row
      float mx = -1e30f;                     // per-lane partial max
#pragma unroll
      for (int kt = 0; kt < 4; kt++) {
        f32x4 sv = s[kt];
        f32x4 bv = *(const f32x4*)(&Bb[j0 + kt * 16 + quad * 4]);
#pragma unroll
        for (int i = 0; i < 4; i++) {
          float x = sv[i] + bv[i];
          if (diag) {
            int key = j0 + kt * 16 + quad * 4 + i;
            if (key > qrow) x = MINV;
          }
          sv[i] = x;
          mx = fmaxf(mx, x);
        }
        s[kt] = sv;
      }
      // defer-max (T13) with PER-LANE partial max: __all() reduces across the
      // wave, so this is equivalent to checking the row-reduced max. The two
      // max-shuffles only run on the rare rescale path.
      if (!__all(mx <= m_i + 8.0f)) {
        mx = fmaxf(mx, __shfl_xor(mx, 16));
        mx = fmaxf(mx, __shfl_xor(mx, 32));   // now per-row max
        const float mn = fmaxf(m_i, mx);
        const float alpha = EXP2F(m_i - mn);
        m_i = mn;
        l_i *= alpha;
#pragma unroll
        for (int mt = 0; mt < 8; mt++) {
          acc[mt][0] *= alpha; acc[mt][1] *= alpha;
          acc[mt][2] *= alpha; acc[mt][3] *= alpha;
        }
      }
      const float mn = m_i;
      float sum = 0.f;
      bf16x4 pf[4];
#pragma unroll
      for (int kt = 0; kt < 4; kt++) {
        f32x4 sv = s[kt];
        bf16x4 p4;
#pragma unroll
        for (int i = 0; i < 4; i++) {
          float pe = EXP2F(sv[i] - mn);
          sum += pe;
          p4[i] = (bf16_t)pe;
        }
        pf[kt] = p4;
      }
      l_i += sum;    // lane-partial; cross-quad reduce deferred to epilogue

      // ---- PV with K=16 MFMA: A = V^T frag (k=quad*4+j via permuted cols),
      //      B = pf (lane-local). acc layout: row=d (mt*16+quad*4+i), col=qrow.
      __builtin_amdgcn_s_setprio(1);
#pragma unroll
      for (int mt = 0; mt < 8; mt++) {
        const char* vr = VbC + (size_t)(mt * 16 + l15) * 128;
        bf16x8 v01 = *(const bf16x8*)(vr + ((quad * 16) ^ rsw));
        bf16x8 v23 = *(const bf16x8*)(vr + ((64 + quad * 16) ^ rsw));
        bf16x4 va = __builtin_shufflevector(v01, v01, 0, 1, 2, 3);
        bf16x4 vb = __builtin_shufflevector(v01, v01, 4, 5, 6, 7);
        bf16x4 vc = __builtin_shufflevector(v23, v23, 0, 1, 2, 3);
        bf16x4 vd = __builtin_shufflevector(v23, v23, 4, 5, 6, 7);
        acc[mt] = mfma16k16(va, pf[0], acc[mt]);
        acc[mt] = mfma16k16(vb, pf[1], acc[mt]);
        acc[mt] = mfma16k16(vc, pf[2], acc[mt]);
        acc[mt] = mfma16k16(vd, pf[3], acc[mt]);
      }
      __builtin_amdgcn_s_setprio(0);
    }

    // ---- stage round r+1 into the other buffer; single barrier per round.
    if (!last) {
      STAGE(cur ^ 1);
      __syncthreads();
      cur ^= 1;
    }
  }

  {
    // Epilogue: reduce the lane-partial l_i across the row's 4 quads (once).
    l_i += __shfl_xor(l_i, 16);
    l_i += __shfl_xor(l_i, 32);
    const float invl = 1.0f / l_i;
    bf16_t* ob = o + ((size_t)(b * LL + q0 + l15)) * (HQ * DHD) + h * DHD + quad * 4;
#pragma unroll
    for (int mt = 0; mt < 8; mt++) {
      f32x4 a = acc[mt];
      bf16x4 w = {(bf16_t)(a[0] * invl), (bf16_t)(a[1] * invl),
                  (bf16_t)(a[2] * invl), (bf16_t)(a[3] * invl)};
      *(bf16x4*)(ob + mt * 16) = w;
    }
  }
}

extern "C" void kernel_launch(void* const* d_in, const int* in_sizes, int n_in,
                              void* d_out, int out_size, void* d_ws, size_t ws_size,
                              hipStream_t stream) {
  const float* hidden = (const float*)d_in[0];
  const int*   amask  = (const int*)d_in[1];
  const float* Wq     = (const float*)d_in[2];
  const float* Wk     = (const float*)d_in[3];
  const float* Wv     = (const float*)d_in[4];
  const float* Wo     = (const float*)d_in[5];
  float* out = (float*)d_out;

  const int M = BB * LL;           // 4096
  const size_t MB = 1u << 20;
  char* ws = (char*)d_ws;
  bf16_t* hid_b   = (bf16_t*)(ws);            // 16 MB  (B,L,D)
  bf16_t* q_ws    = (bf16_t*)(ws + 16 * MB);  // 16 MB
  bf16_t* attn_ws = (bf16_t*)(ws + 32 * MB);  // 16 MB
  bf16_t* k_ws    = (bf16_t*)(ws + 48 * MB);  //  4 MB
  bf16_t* vt_ws   = (bf16_t*)(ws + 52 * MB);  //  4 MB
  bf16_t* wqkv_b  = (bf16_t*)(ws + 56 * MB);  // 12 MB: Wq(8) + Wk(2) + Wv(2)
  bf16_t* wq_b    = wqkv_b;
  bf16_t* wk_b    = (bf16_t*)(ws + 64 * MB);
  bf16_t* wv_b    = (bf16_t*)(ws + 66 * MB);
  bf16_t* wo_b    = (bf16_t*)(ws + 68 * MB);  //  8 MB

  CastArgs ca;
  ca.s[0] = hidden; ca.d[0] = hid_b; ca.n[0] = BB * LL * DDIM;
  ca.s[1] = Wq;     ca.d[1] = wq_b;  ca.n[1] = HQ * DHD * DDIM;
  ca.s[2] = Wk;     ca.d[2] = wk_b;  ca.n[2] = HKV * DHD * DDIM;
  ca.s[3] = Wv;     ca.d[3] = wv_b;  ca.n[3] = HKV * DHD * DDIM;
  ca.s[4] = Wo;     ca.d[4] = wo_b;  ca.n[4] = DDIM * DDIM;
  {
    int maxn = BB * LL * DDIM;
    dim3 g((maxn / 8 + 255) / 256, 5);
    cast5_kernel<<<g, 256, 0, stream>>>(ca);
  }

  gemm_tile<3><<<dim3(3072 / 128, M / 128), 256, 0, stream>>>(
      hid_b, wqkv_b, q_ws, k_ws, vt_ws, M, 3072, DDIM);

  flash_attn2<<<512, 512, 0, stream>>>(q_ws, k_ws, vt_ws, amask, attn_ws);

  gemm_tile<2><<<dim3(DDIM / 128, M / 128), 256, 0, stream>>>(
      attn_ws, wo_b, (void*)out, nullptr, nullptr, M, DDIM, DDIM);
}